// Round 3
// baseline (1056.905 us; speedup 1.0000x reference)
//
#include <hip/hip_runtime.h>
#include <cstdint>

typedef __bf16 bf16;
typedef __bf16 bf16x8 __attribute__((ext_vector_type(8)));
typedef float f32x4 __attribute__((ext_vector_type(4)));

// ---------------- helpers ----------------
__device__ __forceinline__ void gload_lds16(const void* g, void* l) {
  __builtin_amdgcn_global_load_lds(
      (const __attribute__((address_space(1))) unsigned int*)g,
      (__attribute__((address_space(3))) unsigned int*)l, 16, 0, 0);
}

__device__ __forceinline__ float tanh_fast(float x) {
  float ax = fabsf(x);
  float e = __expf(ax + ax);
  float t = 1.0f - 2.0f / (e + 1.0f);
  return x < 0.0f ? -t : t;
}

// ---------------- generic shifted-tap GEMM (m97-style) ----------------
// C[m, co] = sum_{sh,ci} A[n][p+sh][ci] * Bt[co][sh*CI+ci] + bias[co]
// m = n*P + p (P = 1<<logP). A is UNPADDED bf16 [n][P][CI]; rows p+sh outside
// [0,P) are redirected per-lane to the zero page zp (global_load_lds takes
// per-lane source addresses, so an address cndmask implements the halo).
// POOL: max over adjacent row pairs -> out position p>>1 (fused maxpool2).
template<bool POOL>
__global__ __launch_bounds__(256) void gemm_tap(
    const bf16* __restrict__ A, const bf16* __restrict__ Bt,
    const float* __restrict__ bias, bf16* __restrict__ Out,
    const bf16* __restrict__ zp,
    int snA, int logP, int logCI, int shift0, int Ktot, int COt, int snO)
{
  __shared__ __align__(16) bf16 Abuf[128 * 32];
  __shared__ __align__(16) bf16 Bbuf[128 * 32];
  const int tid  = threadIdx.x;
  const int wave = tid >> 6, lane = tid & 63;
  const int wr = wave >> 1, wc = wave & 1;
  const int m0  = blockIdx.y << 7;
  const int co0 = blockIdx.x << 7;
  const int P      = 1 << logP;
  const int Pmask  = P - 1;
  const int CI     = 1 << logCI;
  const int CImask = CI - 1;
  f32x4 acc[4][4] = {};

  const int r0  = tid >> 2;             // rows 0..63   (chunk rep 0)
  const int r1  = r0 + 64;              // rows 64..127 (chunk rep 1)
  const int pt0 = (tid & 3) << 3;       // element offset within row (8 bf16 = 16B)
  bf16* ldsA0 = &Abuf[wave * 512];
  bf16* ldsA1 = &Abuf[2048 + wave * 512];
  bf16* ldsB0 = &Bbuf[wave * 512];
  bf16* ldsB1 = &Bbuf[2048 + wave * 512];

  for (int kb = 0; kb < Ktot; kb += 32) {
    int sh  = (kb >> logCI) + shift0;
    int ci0 = kb & CImask;
    {
      int m = m0 + r0;
      int n = m >> logP, p = m & Pmask;
      int row = p + sh;
      const bf16* src = ((unsigned)row < (unsigned)P)
                          ? (A + n * snA + row * CI + ci0 + pt0) : (zp + pt0);
      gload_lds16(src, ldsA0);
      gload_lds16(Bt + (co0 + r0) * Ktot + kb + pt0, ldsB0);
    }
    {
      int m = m0 + r1;
      int n = m >> logP, p = m & Pmask;
      int row = p + sh;
      const bf16* src = ((unsigned)row < (unsigned)P)
                          ? (A + n * snA + row * CI + ci0 + pt0) : (zp + pt0);
      gload_lds16(src, ldsA1);
      gload_lds16(Bt + (co0 + r1) * Ktot + kb + pt0, ldsB1);
    }
    __syncthreads();
    const int frow = lane & 15, fk = (lane >> 4) << 3;
    bf16x8 af[4], bg[4];
#pragma unroll
    for (int i = 0; i < 4; ++i) {
      af[i] = *(const bf16x8*)&Abuf[((wr << 6) + (i << 4) + frow) * 32 + fk];
      bg[i] = *(const bf16x8*)&Bbuf[((wc << 6) + (i << 4) + frow) * 32 + fk];
    }
#pragma unroll
    for (int i = 0; i < 4; ++i)
#pragma unroll
      for (int j = 0; j < 4; ++j)
        acc[i][j] = __builtin_amdgcn_mfma_f32_16x16x32_bf16(af[i], bg[j], acc[i][j], 0, 0, 0);
    __syncthreads();
  }

  // epilogue: C/D layout col=lane&15, row=(lane>>4)*4+reg  [m89-verified]
  const int colL = lane & 15;
  const int rq   = (lane >> 4) << 2;
#pragma unroll
  for (int i = 0; i < 4; ++i) {
    int m = m0 + (wr << 6) + (i << 4) + rq;
    int n = m >> logP, p = m & Pmask;
#pragma unroll
    for (int j = 0; j < 4; ++j) {
      int gco = co0 + (wc << 6) + (j << 4) + colL;
      float bv = bias[gco];
      if (POOL) {
        float v0 = fmaxf(acc[i][j][0], acc[i][j][1]) + bv;
        float v1 = fmaxf(acc[i][j][2], acc[i][j][3]) + bv;
        bf16* o = Out + n * snO + (p >> 1) * COt + gco;
        o[0]   = (bf16)v0;
        o[COt] = (bf16)v1;
      } else {
#pragma unroll
        for (int r = 0; r < 4; ++r)
          Out[n * snO + (p + r) * COt + gco] = (bf16)(acc[i][j][r] + bv);
      }
    }
  }
}

// ---------------- batch fp32 -> bf16 ----------------
__global__ void kcvt(const float* __restrict__ src, bf16* __restrict__ dst) {
  int idx = (blockIdx.x * 256 + threadIdx.x) * 8;     // 33554432 elems
  float4 a = *(const float4*)&src[idx];
  float4 b = *(const float4*)&src[idx + 4];
  bf16x8 v;
  v[0] = (bf16)a.x; v[1] = (bf16)a.y; v[2] = (bf16)a.z; v[3] = (bf16)a.w;
  v[4] = (bf16)b.x; v[5] = (bf16)b.y; v[6] = (bf16)b.z; v[7] = (bf16)b.w;
  *(bf16x8*)&dst[idx] = v;
}

// ---------------- prep kernels (fp32 weights -> bf16, re-layout) ----------------
// Bt1[co][tap][ci] = conv1_w[co][ci][tap]
__global__ void prep_bt1(const float* __restrict__ w, bf16* __restrict__ B) {
  int idx = blockIdx.x * 256 + threadIdx.x;          // 512*5*1024
  int co = idx / 5120;
  int rem = idx - co * 5120;
  int t = rem >> 10, ci = rem & 1023;
  B[idx] = (bf16)w[co * 5120 + ci * 5 + t];
}
__global__ void prep_bt2(const float* __restrict__ w, bf16* __restrict__ B) {
  int idx = blockIdx.x * 256 + threadIdx.x;          // 256*5*512
  int co = idx / 2560;
  int rem = idx - co * 2560;
  int t = rem >> 9, ci = rem & 511;
  B[idx] = (bf16)w[co * 2560 + ci * 5 + t];
}
// Bqkc[co][ci], co<256: sa_wq, <512: sa_wk, <768: ca_wk (all stored [in][out])
__global__ void prep_bqkc(const float* __restrict__ wq, const float* __restrict__ wk,
                          const float* __restrict__ wkc, bf16* __restrict__ B) {
  int idx = blockIdx.x * 256 + threadIdx.x;          // 768*256
  int co = idx >> 8, ci = idx & 255;
  float v;
  if (co < 256)      v = wq[ci * 256 + co];
  else if (co < 512) v = wk[ci * 256 + (co - 256)];
  else               v = wkc[ci * 256 + (co - 512)];
  B[idx] = (bf16)v;
}
// deconv weights, parity folded into out-channels; taps t=0,1,2 <-> sh=-1,0,+1
// even j (par0): sh=0 -> ki=1, sh=-1 -> ki=3 ; odd j (par1): sh=+1 -> ki=0, sh=0 -> ki=2
__global__ void prep_btd1(const float* __restrict__ w, bf16* __restrict__ B) {
  int idx = blockIdx.x * 256 + threadIdx.x;          // 1024*3*1024
  int co = idx / 3072;
  int rem = idx - co * 3072;
  int t = rem >> 10, ci = rem & 1023;
  int par = co >> 9, c = co & 511;
  int ki = -1;
  if (par == 0) { if (t == 1) ki = 1; else if (t == 0) ki = 3; }
  else          { if (t == 2) ki = 0; else if (t == 1) ki = 2; }
  B[idx] = (ki >= 0) ? (bf16)w[ci * 2048 + c * 4 + ki] : (bf16)0.0f;
}
__global__ void prep_btd2(const float* __restrict__ w, bf16* __restrict__ B) {
  int idx = blockIdx.x * 256 + threadIdx.x;          // 256*3*512
  int co = idx / 1536;
  int rem = idx - co * 1536;
  int t = rem >> 9, ci = rem & 511;
  int par = co >> 7, c = co & 127;
  int ki = -1;
  if (par == 0) { if (t == 1) ki = 1; else if (t == 0) ki = 3; }
  else          { if (t == 2) ki = 0; else if (t == 1) ki = 2; }
  B[idx] = (ki >= 0) ? (bf16)w[ci * 512 + c * 4 + ki] : (bf16)0.0f;
}
__global__ void prep_bts1(const float* __restrict__ w, bf16* __restrict__ B) {
  int idx = blockIdx.x * 256 + threadIdx.x;          // 128*128
  int co = idx >> 7, ci = idx & 127;
  B[idx] = (bf16)w[ci * 128 + co];
}
// biases -> f32: [0,512) c1 | [512,768) c2 | [768,1536) qkc | [1536,2560) d1 dup |
// [2560,2816) d2 dup | [2816,2944) zeros (sim1 bias + reused as bf16 zero page)
__global__ void prep_bias(const float* c1b, const float* c2b, const float* sabq,
                          const float* sabk, const float* cabk, const float* d1b,
                          const float* d2b, float* __restrict__ bias) {
  int i = blockIdx.x * 256 + threadIdx.x;
  if (i >= 2944) return;
  float v;
  if (i < 512)       v = c1b[i];
  else if (i < 768)  v = c2b[i - 512];
  else if (i < 1024) v = sabq[i - 768];
  else if (i < 1280) v = sabk[i - 1024];
  else if (i < 1536) v = cabk[i - 1280];
  else if (i < 2560) v = d1b[(i - 1536) & 511];
  else if (i < 2816) v = d2b[(i - 2560) & 127];
  else               v = 0.0f;
  bias[i] = v;
}

// cq[c][b][h] = (concept_c[b] @ ca_wq)[h] + ca_bq[h]      (f32, 2*8*256)
// uu[c][b][m] = (concept_c[b] @ sim2_w)[m] * mlp_w[m]     (f32, 2*8*128)
__global__ __launch_bounds__(256) void kcq(
    const float* __restrict__ c1, const float* __restrict__ c2,
    const float* __restrict__ ca_wq, const float* __restrict__ ca_bq,
    const float* __restrict__ sim2_w, const float* __restrict__ mlp_w,
    float* __restrict__ cq, float* __restrict__ uu)
{
  int tid = threadIdx.x;
  for (int o = tid; o < 4096; o += 256) {
    int c = o >> 11, b = (o >> 8) & 7, h = o & 255;
    const float* cc = (c ? c2 : c1) + b * 300;
    float acc = ca_bq[h];
    for (int j = 0; j < 300; ++j)
      acc += cc[j] * ca_wq[j * 256 + h];
    cq[o] = acc;
  }
  for (int o = tid; o < 2048; o += 256) {
    int c = o >> 10, b = (o >> 7) & 7, m = o & 127;
    const float* cc = (c ? c2 : c1) + b * 300;
    float acc = 0.0f;
    for (int j = 0; j < 300; ++j)
      acc += cc[j] * sim2_w[j * 128 + m];
    uu[o] = acc * mlp_w[m];
  }
}

// ---------------- fused additive attention (one block per n) ----------------
// builds ar[n][q][0:256)=tmp2, [256:512)=self_res, [512:768)=c1_res, [768:1024)=c2_res
__global__ __launch_bounds__(256) void kattn(
    const bf16* __restrict__ tmp2, const bf16* __restrict__ qkc,
    const float* __restrict__ sa_v, const float* __restrict__ sa_vb,
    const float* __restrict__ ca_v, const float* __restrict__ ca_vb,
    const float* __restrict__ cq, const int* __restrict__ seg,
    bf16* __restrict__ ar)
{
  const int n = blockIdx.x, tid = threadIdx.x;
  __shared__ __align__(16) bf16 t2[32 * 264];
  __shared__ __align__(16) bf16 bufA[32 * 264];
  __shared__ __align__(16) bf16 bufB[32 * 264];
  __shared__ float sv_s[256], cv_s[256];
  __shared__ float sbc[66];
  __shared__ float sbs[32 * 33];
  const int sl = seg[n];

  // phase 1: load tmp2 + ckp + score vectors
#pragma unroll
  for (int rr = 0; rr < 4; ++rr) {
    int q = tid + (rr << 8);
    int k = q >> 5, c8 = (q & 31) << 3;
    *(uint4*)&t2[k * 264 + c8]   = *(const uint4*)&tmp2[n * 8192 + k * 256 + c8];
    *(uint4*)&bufA[k * 264 + c8] = *(const uint4*)&qkc[n * 24576 + k * 768 + 512 + c8];
  }
  sv_s[tid] = sa_v[tid];
  cv_s[tid] = ca_v[tid];
  __syncthreads();

  // phase 2: concept scores (2 concepts x 32 keys)
  if (tid < 64) {
    int c = tid >> 5, k = tid & 31;
    const float* cqr = cq + (c * 8 + (n >> 5)) * 256;
    float acc = 0.0f;
    for (int h = 0; h < 256; ++h)
      acc += tanh_fast(cqr[h] + (float)bufA[k * 264 + h]) * cv_s[h];
    float sc = acc + ca_vb[0];
    sbc[c * 33 + k] = (sl > (k << 2)) ? sc : -1e9f;
  }
  __syncthreads();

  // phase 3: load qp/kp (all threads) + concept softmax (2 threads)
#pragma unroll
  for (int rr = 0; rr < 4; ++rr) {
    int q = tid + (rr << 8);
    int k = q >> 5, c8 = (q & 31) << 3;
    *(uint4*)&bufB[k * 264 + c8] = *(const uint4*)&qkc[n * 24576 + k * 768 + c8];        // qp
    *(uint4*)&bufA[k * 264 + c8] = *(const uint4*)&qkc[n * 24576 + k * 768 + 256 + c8];  // kp
  }
  if (tid < 2) {
    float* row = &sbc[tid * 33];
    float mx = -1e30f;
    for (int k = 0; k < 32; ++k) mx = fmaxf(mx, row[k]);
    float sum = 0.0f;
    for (int k = 0; k < 32; ++k) { float e = __expf(row[k] - mx); row[k] = e; sum += e; }
    float inv = 1.0f / sum;
    for (int k = 0; k < 32; ++k) row[k] *= inv;
  }
  __syncthreads();

  // phase 4a: concept result + write tmp2/c1/c2 into ar
  {
    int col = tid;
    float rr0 = 0.0f, rr1 = 0.0f;
    for (int k = 0; k < 32; ++k) {
      float tv = (float)t2[k * 264 + col];
      rr0 += sbc[k] * tv;
      rr1 += sbc[33 + k] * tv;
    }
    bf16 b0 = (bf16)rr0, b1 = (bf16)rr1;
    bf16* arn = ar + n * 32768;
    for (int q = 0; q < 32; ++q) {
      arn[q * 1024 + col]       = t2[q * 264 + col];
      arn[q * 1024 + 512 + col] = b0;
      arn[q * 1024 + 768 + col] = b1;
    }
  }
  // phase 4b: self-attention scores (4 (q,k) pairs per thread)
  {
    float svb = sa_vb[0];
#pragma unroll
    for (int rr = 0; rr < 4; ++rr) {
      int id = tid + (rr << 8);
      int q = id >> 5, k = id & 31;
      float acc = 0.0f;
      for (int h = 0; h < 256; ++h)
        acc += tanh_fast((float)bufB[q * 264 + h] + (float)bufA[k * 264 + h]) * sv_s[h];
      float sc = acc + svb;
      sbs[q * 33 + k] = (sl > (k << 2)) ? sc : -1e9f;
    }
  }
  __syncthreads();

  // phase 5: self softmax (32 rows)
  if (tid < 32) {
    float* row = &sbs[tid * 33];
    float mx = -1e30f;
    for (int k = 0; k < 32; ++k) mx = fmaxf(mx, row[k]);
    float sum = 0.0f;
    for (int k = 0; k < 32; ++k) { float e = __expf(row[k] - mx); row[k] = e; sum += e; }
    float inv = 1.0f / sum;
    for (int k = 0; k < 32; ++k) row[k] *= inv;
  }
  __syncthreads();

  // phase 6: self_res -> ar[256:512)
  {
    int col = tid;
    bf16* arn = ar + n * 32768;
    for (int q = 0; q < 32; ++q) {
      float acc = 0.0f;
      for (int k = 0; k < 32; ++k)
        acc += sbs[q * 33 + k] * (float)t2[k * 264 + col];
      arn[q * 1024 + 256 + col] = (bf16)acc;
    }
  }
}

// ---------------- final score ----------------
__global__ __launch_bounds__(256) void kscore(
    const bf16* __restrict__ sim1, const float* __restrict__ uu,
    const float* __restrict__ mlp_b, float* __restrict__ out)
{
  int row = blockIdx.x * 256 + threadIdx.x;   // [0, 32768)
  int b = row >> 12;
  const float* u0 = uu + b * 128;
  const float* u1 = uu + 1024 + b * 128;
  const bf16* sr = sim1 + row * 128;
  float d0 = 0.0f, d1 = 0.0f;
  for (int mm = 0; mm < 128; mm += 8) {
    bf16x8 v = *(const bf16x8*)&sr[mm];
#pragma unroll
    for (int t = 0; t < 8; ++t) {
      float sv = (float)v[t];
      d0 += sv * u0[mm + t];
      d1 += sv * u1[mm + t];
    }
  }
  float bb = mlp_b[0];
  out[row]         = 1.0f / (1.0f + __expf(-(d0 + bb)));
  out[32768 + row] = 1.0f / (1.0f + __expf(-(d1 + bb)));
}

// ---------------- launch ----------------
extern "C" void kernel_launch(void* const* d_in, const int* in_sizes, int n_in,
                              void* d_out, int out_size, void* d_ws, size_t ws_size,
                              hipStream_t stream) {
  const float* batch    = (const float*)d_in[0];
  const float* concept1 = (const float*)d_in[1];
  const float* concept2 = (const float*)d_in[2];
  const int*   seg      = (const int*)d_in[3];
  const float* conv1_w  = (const float*)d_in[4];
  const float* conv1_b  = (const float*)d_in[5];
  const float* conv2_w  = (const float*)d_in[6];
  const float* conv2_b  = (const float*)d_in[7];
  const float* sa_wq    = (const float*)d_in[8];
  const float* sa_bq    = (const float*)d_in[9];
  const float* sa_wk    = (const float*)d_in[10];
  const float* sa_bk    = (const float*)d_in[11];
  const float* sa_v     = (const float*)d_in[12];
  const float* sa_vb    = (const float*)d_in[13];
  const float* ca_wq    = (const float*)d_in[14];
  const float* ca_bq    = (const float*)d_in[15];
  const float* ca_wk    = (const float*)d_in[16];
  const float* ca_bk    = (const float*)d_in[17];
  const float* ca_v     = (const float*)d_in[18];
  const float* ca_vb    = (const float*)d_in[19];
  const float* dc1_w    = (const float*)d_in[20];
  const float* dc1_b    = (const float*)d_in[21];
  const float* dc2_w    = (const float*)d_in[22];
  const float* dc2_b    = (const float*)d_in[23];
  const float* sim1_w   = (const float*)d_in[24];
  const float* sim2_w   = (const float*)d_in[25];
  const float* mlp_w    = (const float*)d_in[26];
  const float* mlp_b    = (const float*)d_in[27];

  char* ws = (char*)d_ws;
  // Workspace layout (102.2 MB total; lifetime-based aliasing):
  //  [0,67.1M)        batch_bf16 [256][128][1024]   (dead after conv1)
  //    aliased after conv1/conv2:
  //    [0,12.6M)       qkc [256][32][768]
  //    [12.6M,29.4M)   ar  [256][32][1024]
  //    [29.4M,46.1M)   d1  [256][64][512x2par]
  //    [46.1M,54.5M)   rbuf[256][128][128]
  //    [54.5M,62.9M)   sim1b [32768][128]
  //  [67.1M,83.9M)    t1 [256][64][512]
  //  [83.9M,88.1M)    tmp2 [256][32][256]
  //  [88.1M,...]      weights, biases, cq, uu
  bf16* bb16  = (bf16*)(ws + 0);
  bf16* qkcb  = (bf16*)(ws + 0);
  bf16* arb   = (bf16*)(ws + 12582912);
  bf16* d1    = (bf16*)(ws + 29360128);
  bf16* rbuf  = (bf16*)(ws + 46137344);
  bf16* sim1b = (bf16*)(ws + 54525952);
  bf16* t1    = (bf16*)(ws + 67108864);
  bf16* tmp2b = (bf16*)(ws + 83886080);
  bf16* Bt1   = (bf16*)(ws + 88080384);
  bf16* Bt2   = (bf16*)(ws + 93323264);
  bf16* Bqkc  = (bf16*)(ws + 94633984);
  bf16* Btd1  = (bf16*)(ws + 95027200);
  bf16* Btd2  = (bf16*)(ws + 101318656);
  bf16* Bts1  = (bf16*)(ws + 102105088);
  float* biasall = (float*)(ws + 102137856);
  float* cqb  = (float*)(ws + 102149632);
  float* uub  = (float*)(ws + 102166016);
  const bf16* zp = (const bf16*)(biasall + 2816);  // 128 f32 zeros = 256 bf16 zeros
  float* outp = (float*)d_out;

  // weight/bias prep (prep_bias also produces the zero page)
  prep_bias<<<12, 256, 0, stream>>>(conv1_b, conv2_b, sa_bq, sa_bk, ca_bk, dc1_b, dc2_b, biasall);
  prep_bt1<<<10240, 256, 0, stream>>>(conv1_w, Bt1);
  prep_bt2<<<2560, 256, 0, stream>>>(conv2_w, Bt2);
  prep_bqkc<<<768, 256, 0, stream>>>(sa_wq, sa_wk, ca_wk, Bqkc);
  prep_btd1<<<12288, 256, 0, stream>>>(dc1_w, Btd1);
  prep_btd2<<<1536, 256, 0, stream>>>(dc2_w, Btd2);
  prep_bts1<<<64, 256, 0, stream>>>(sim1_w, Bts1);
  kcq<<<1, 256, 0, stream>>>(concept1, concept2, ca_wq, ca_bq, sim2_w, mlp_w, cqb, uub);

  // batch fp32 -> bf16
  kcvt<<<16384, 256, 0, stream>>>(batch, bb16);

  // conv1 + pool: [256*128, 5120] x [5120, 512] -> t1 [256][64][512]
  gemm_tap<true><<<dim3(4, 256), 256, 0, stream>>>(
      bb16, Bt1, biasall + 0, t1, zp, 131072, 7, 10, -2, 5120, 512, 32768);

  // conv2 + pool -> tmp2 [256][32][256]
  gemm_tap<true><<<dim3(2, 128), 256, 0, stream>>>(
      t1, Bt2, biasall + 512, tmp2b, zp, 32768, 6, 9, -2, 2560, 256, 8192);

  // fused q/k/ck projection -> qkc [256][32][768]   (aliases dead batch_bf16)
  gemm_tap<false><<<dim3(6, 64), 256, 0, stream>>>(
      tmp2b, Bqkc, biasall + 768, qkcb, zp, 8192, 5, 8, 0, 256, 768, 24576);

  // attention -> ar [256][32][1024]
  kattn<<<256, 256, 0, stream>>>(tmp2b, qkcb, sa_v, sa_vb, ca_v, ca_vb, cqb, seg, arb);

  // deconv1 -> d1 [256][64][1024] (parity-interleaved rows of 512)
  gemm_tap<false><<<dim3(8, 64), 256, 0, stream>>>(
      arb, Btd1, biasall + 1536, d1, zp, 32768, 5, 10, -1, 3072, 1024, 32768);

  // deconv2 -> rbuf [256][64][256] (parity-interleaved rows of 128)
  gemm_tap<false><<<dim3(2, 128), 256, 0, stream>>>(
      d1, Btd2, biasall + 2560, rbuf, zp, 32768, 6, 9, -1, 1536, 256, 16384);

  // sim1 = r @ sim1_w -> sim1b [32768][128]
  gemm_tap<false><<<dim3(1, 256), 256, 0, stream>>>(
      rbuf, Bts1, biasall + 2816, sim1b, zp, 16384, 7, 7, 0, 128, 128, 16384);

  // final scores (fp32 out)
  kscore<<<128, 256, 0, stream>>>(sim1b, uub, mlp_b, outp);
}

// Round 4
// 838.253 us; speedup vs baseline: 1.2608x; 1.2608x over previous
//
#include <hip/hip_runtime.h>
#include <cstdint>

typedef __bf16 bf16;
typedef __bf16 bf16x8 __attribute__((ext_vector_type(8)));
typedef float f32x4 __attribute__((ext_vector_type(4)));

// ---------------- helpers ----------------
__device__ __forceinline__ void gload_lds16(const void* g, void* l) {
  __builtin_amdgcn_global_load_lds(
      (const __attribute__((address_space(1))) unsigned int*)g,
      (__attribute__((address_space(3))) unsigned int*)l, 16, 0, 0);
}

__device__ __forceinline__ float tanh_fast(float x) {
  float ax = fabsf(x);
  float e = __expf(ax + ax);
  float t = 1.0f - 2.0f / (e + 1.0f);
  return x < 0.0f ? -t : t;
}

// ---------------- generic shifted-tap GEMM (m97-style, split-tap K-loop) ----
// C[m, co] = sum_{tap,ci} A[n][p+tap+shift0][ci] * Bt[co][tap*CI+ci] + bias[co]
// m = n*P + p (P = 1<<logP). A is UNPADDED bf16 [n][P][CI]; out-of-range rows
// redirect to zero page zp. Outer loop over taps (addresses hoisted, validity
// select once per tap), inner loop over kc with bare pointer increments.
// XOR k-group swizzle kills ds_read_b128 bank conflicts (2-way max = free).
// POOL: max over adjacent row pairs -> out position p>>1 (fused maxpool2).
template<bool POOL>
__global__ __launch_bounds__(256) void gemm_tap(
    const bf16* __restrict__ A, const bf16* __restrict__ Bt,
    const float* __restrict__ bias, bf16* __restrict__ Out,
    const bf16* __restrict__ zp,
    int snA, int logP, int logCI, int shift0, int ntaps, int kcPerTap,
    int Ktot, int COt, int snO)
{
  __shared__ __align__(16) bf16 Abuf[128 * 32];
  __shared__ __align__(16) bf16 Bbuf[128 * 32];
  const int tid  = threadIdx.x;
  const int wave = tid >> 6, lane = tid & 63;
  const int wr = wave >> 1, wc = wave & 1;
  const int m0  = blockIdx.y << 7;
  const int co0 = blockIdx.x << 7;
  const int P      = 1 << logP;
  const int Pmask  = P - 1;
  const int CI     = 1 << logCI;
  f32x4 acc[4][4] = {};

  // staging lane map: row rowL (0..63; +64 for rep1), k-group kg swizzled
  const int rowL = tid >> 2;
  const int kg   = tid & 3;
  const int fOff = ((kg ^ ((rowL + (rowL >> 2)) & 3)) << 3);  // elem offset in 32-chunk
  bf16* ldsA0 = &Abuf[wave * 512];
  bf16* ldsA1 = &Abuf[2048 + wave * 512];
  bf16* ldsB0 = &Bbuf[wave * 512];
  bf16* ldsB1 = &Bbuf[2048 + wave * 512];

  // A row decompose (per rep, tap-independent)
  const int mA0 = m0 + rowL,      nA0 = mA0 >> logP, pA0 = mA0 & Pmask;
  const int mA1 = m0 + rowL + 64, nA1 = mA1 >> logP, pA1 = mA1 & Pmask;
  const bf16* baseA0 = A + nA0 * snA + fOff;
  const bf16* baseA1 = A + nA1 * snA + fOff;
  const bf16* baseB0 = Bt + (co0 + rowL) * Ktot + fOff;
  const bf16* baseB1 = Bt + (co0 + rowL + 64) * Ktot + fOff;
  const bf16* zsrc = zp + fOff;

  // fragment read offsets (match the staging swizzle; 2-way banks = free)
  const int frow = lane & 15;
  const int rdOff = ((((lane >> 4) ^ ((frow + (frow >> 2)) & 3))) << 3);

  for (int tap = 0; tap < ntaps; ++tap) {
    const int sh = tap + shift0;
    const int rA0 = pA0 + sh, rA1 = pA1 + sh;
    const bf16* pa0 = ((unsigned)rA0 < (unsigned)P) ? (baseA0 + rA0 * CI) : zsrc;
    const bf16* pa1 = ((unsigned)rA1 < (unsigned)P) ? (baseA1 + rA1 * CI) : zsrc;
    const bool zA0 = !((unsigned)rA0 < (unsigned)P);
    const bool zA1 = !((unsigned)rA1 < (unsigned)P);
    const bf16* pb0 = baseB0 + tap * CI;
    const bf16* pb1 = baseB1 + tap * CI;

    for (int kc = 0; kc < kcPerTap; ++kc) {
      gload_lds16(pa0, ldsA0);
      gload_lds16(pb0, ldsB0);
      gload_lds16(pa1, ldsA1);
      gload_lds16(pb1, ldsB1);
      if (!zA0) pa0 += 32;
      if (!zA1) pa1 += 32;
      pb0 += 32; pb1 += 32;
      __syncthreads();
      bf16x8 af[4], bg[4];
#pragma unroll
      for (int i = 0; i < 4; ++i) {
        af[i] = *(const bf16x8*)&Abuf[((wr << 6) + (i << 4) + frow) * 32 + rdOff];
        bg[i] = *(const bf16x8*)&Bbuf[((wc << 6) + (i << 4) + frow) * 32 + rdOff];
      }
#pragma unroll
      for (int i = 0; i < 4; ++i)
#pragma unroll
        for (int j = 0; j < 4; ++j)
          acc[i][j] = __builtin_amdgcn_mfma_f32_16x16x32_bf16(af[i], bg[j], acc[i][j], 0, 0, 0);
      __syncthreads();
    }
  }

  // epilogue: C/D layout col=lane&15, row=(lane>>4)*4+reg  [m89-verified]
  const int colL = lane & 15;
  const int rq   = (lane >> 4) << 2;
#pragma unroll
  for (int i = 0; i < 4; ++i) {
    int m = m0 + (wr << 6) + (i << 4) + rq;
    int n = m >> logP, p = m & Pmask;
#pragma unroll
    for (int j = 0; j < 4; ++j) {
      int gco = co0 + (wc << 6) + (j << 4) + colL;
      float bv = bias[gco];
      if (POOL) {
        float v0 = fmaxf(acc[i][j][0], acc[i][j][1]) + bv;
        float v1 = fmaxf(acc[i][j][2], acc[i][j][3]) + bv;
        bf16* o = Out + n * snO + (p >> 1) * COt + gco;
        o[0]   = (bf16)v0;
        o[COt] = (bf16)v1;
      } else {
#pragma unroll
        for (int r = 0; r < 4; ++r)
          Out[n * snO + (p + r) * COt + gco] = (bf16)(acc[i][j][r] + bv);
      }
    }
  }
}

// ---------------- batch fp32 -> bf16 ----------------
__global__ void kcvt(const float* __restrict__ src, bf16* __restrict__ dst) {
  int idx = (blockIdx.x * 256 + threadIdx.x) * 8;     // 33554432 elems
  float4 a = *(const float4*)&src[idx];
  float4 b = *(const float4*)&src[idx + 4];
  bf16x8 v;
  v[0] = (bf16)a.x; v[1] = (bf16)a.y; v[2] = (bf16)a.z; v[3] = (bf16)a.w;
  v[4] = (bf16)b.x; v[5] = (bf16)b.y; v[6] = (bf16)b.z; v[7] = (bf16)b.w;
  *(bf16x8*)&dst[idx] = v;
}

// ---------------- fused prep: all weight re-layouts + biases + cq/uu --------
// idx ranges: [0,3072) bias | [3072,2624512) Bt1 | [2624512,3279872) Bt2 |
// [3279872,3476480) Bqkc | [3476480,6622208) Btd1 | [6622208,7015424) Btd2 |
// [7015424,7031808) Bts1. Blocks >= 27468 do cq (16 blocks) + uu (8 blocks).
__global__ __launch_bounds__(256) void prep_all(
    const float* __restrict__ conv1_w, const float* __restrict__ conv2_w,
    const float* __restrict__ sa_wq, const float* __restrict__ sa_wk,
    const float* __restrict__ ca_wk, const float* __restrict__ dc1_w,
    const float* __restrict__ dc2_w, const float* __restrict__ sim1_w,
    const float* __restrict__ c1b, const float* __restrict__ c2b,
    const float* __restrict__ sabq, const float* __restrict__ sabk,
    const float* __restrict__ cabk, const float* __restrict__ d1b,
    const float* __restrict__ d2b,
    const float* __restrict__ c1, const float* __restrict__ c2,
    const float* __restrict__ ca_wq, const float* __restrict__ ca_bq,
    const float* __restrict__ sim2_w, const float* __restrict__ mlp_w,
    bf16* __restrict__ Bt1, bf16* __restrict__ Bt2, bf16* __restrict__ Bqkc,
    bf16* __restrict__ Btd1, bf16* __restrict__ Btd2, bf16* __restrict__ Bts1,
    float* __restrict__ bias, float* __restrict__ cq, float* __restrict__ uu)
{
  const int blk = blockIdx.x;
  if (blk < 27468) {
    int idx = blk * 256 + threadIdx.x;
    if (idx < 3072) {
      // biases -> f32: [0,512) c1 | [512,768) c2 | [768,1536) qkc |
      // [1536,2560) d1 dup | [2560,2816) d2 dup | [2816,2944) zeros
      if (idx < 2944) {
        float v;
        if (idx < 512)       v = c1b[idx];
        else if (idx < 768)  v = c2b[idx - 512];
        else if (idx < 1024) v = sabq[idx - 768];
        else if (idx < 1280) v = sabk[idx - 1024];
        else if (idx < 1536) v = cabk[idx - 1280];
        else if (idx < 2560) v = d1b[(idx - 1536) & 511];
        else if (idx < 2816) v = d2b[(idx - 2560) & 127];
        else                 v = 0.0f;
        bias[idx] = v;
      }
    } else if (idx < 2624512) {
      // Bt1[co][tap][ci] = conv1_w[co][ci][tap]
      int i = idx - 3072;
      int co = i / 5120, rem = i - co * 5120;
      int t = rem >> 10, ci = rem & 1023;
      Bt1[i] = (bf16)conv1_w[co * 5120 + ci * 5 + t];
    } else if (idx < 3279872) {
      int i = idx - 2624512;
      int co = i / 2560, rem = i - co * 2560;
      int t = rem >> 9, ci = rem & 511;
      Bt2[i] = (bf16)conv2_w[co * 2560 + ci * 5 + t];
    } else if (idx < 3476480) {
      // Bqkc[co][ci]: co<256 sa_wq | <512 sa_wk | <768 ca_wk ([in][out] stored)
      int i = idx - 3279872;
      int co = i >> 8, ci = i & 255;
      float v;
      if (co < 256)      v = sa_wq[ci * 256 + co];
      else if (co < 512) v = sa_wk[ci * 256 + (co - 256)];
      else               v = ca_wk[ci * 256 + (co - 512)];
      Bqkc[i] = (bf16)v;
    } else if (idx < 6622208) {
      // deconv1 parity fold: even co: t1->ki1, t0->ki3; odd co: t2->ki0, t1->ki2
      int i = idx - 3476480;
      int co = i / 3072, rem = i - co * 3072;
      int t = rem >> 10, ci = rem & 1023;
      int par = co >> 9, c = co & 511;
      int ki = -1;
      if (par == 0) { if (t == 1) ki = 1; else if (t == 0) ki = 3; }
      else          { if (t == 2) ki = 0; else if (t == 1) ki = 2; }
      Btd1[i] = (ki >= 0) ? (bf16)dc1_w[ci * 2048 + c * 4 + ki] : (bf16)0.0f;
    } else if (idx < 7015424) {
      int i = idx - 6622208;
      int co = i / 1536, rem = i - co * 1536;
      int t = rem >> 9, ci = rem & 511;
      int par = co >> 7, c = co & 127;
      int ki = -1;
      if (par == 0) { if (t == 1) ki = 1; else if (t == 0) ki = 3; }
      else          { if (t == 2) ki = 0; else if (t == 1) ki = 2; }
      Btd2[i] = (ki >= 0) ? (bf16)dc2_w[ci * 512 + c * 4 + ki] : (bf16)0.0f;
    } else {
      int i = idx - 7015424;
      int co = i >> 7, ci = i & 127;
      Bts1[i] = (bf16)sim1_w[ci * 128 + co];
    }
  } else {
    int sub = blk - 27468;
    if (sub < 16) {
      // cq[c][b][h] = concept_c[b] @ ca_wq + ca_bq   (4096 outs)
      int o = sub * 256 + threadIdx.x;
      int c = o >> 11, b = (o >> 8) & 7, h = o & 255;
      const float* cc = (c ? c2 : c1) + b * 300;
      float acc = ca_bq[h];
      for (int j = 0; j < 300; ++j)
        acc += cc[j] * ca_wq[j * 256 + h];
      cq[o] = acc;
    } else {
      // uu[c][b][m] = (concept_c[b] @ sim2_w) * mlp_w   (2048 outs)
      int o = (sub - 16) * 256 + threadIdx.x;
      int c = o >> 10, b = (o >> 7) & 7, m = o & 127;
      const float* cc = (c ? c2 : c1) + b * 300;
      float acc = 0.0f;
      for (int j = 0; j < 300; ++j)
        acc += cc[j] * sim2_w[j * 128 + m];
      uu[o] = acc * mlp_w[m];
    }
  }
}

// ---------------- fused additive attention (one block per n) ----------------
// builds ar[n][q][0:256)=tmp2, [256:512)=self_res, [512:768)=c1_res, [768:1024)=c2_res
__global__ __launch_bounds__(256) void kattn(
    const bf16* __restrict__ tmp2, const bf16* __restrict__ qkc,
    const float* __restrict__ sa_v, const float* __restrict__ sa_vb,
    const float* __restrict__ ca_v, const float* __restrict__ ca_vb,
    const float* __restrict__ cq, const int* __restrict__ seg,
    bf16* __restrict__ ar)
{
  const int n = blockIdx.x, tid = threadIdx.x;
  __shared__ __align__(16) bf16 t2[32 * 264];
  __shared__ __align__(16) bf16 bufA[32 * 264];
  __shared__ __align__(16) bf16 bufB[32 * 264];
  __shared__ float sv_s[256], cv_s[256];
  __shared__ float sbc[66];
  __shared__ float sbs[32 * 33];
  const int sl = seg[n];

  // phase 1: load tmp2 + ckp + score vectors
#pragma unroll
  for (int rr = 0; rr < 4; ++rr) {
    int q = tid + (rr << 8);
    int k = q >> 5, c8 = (q & 31) << 3;
    *(uint4*)&t2[k * 264 + c8]   = *(const uint4*)&tmp2[n * 8192 + k * 256 + c8];
    *(uint4*)&bufA[k * 264 + c8] = *(const uint4*)&qkc[n * 24576 + k * 768 + 512 + c8];
  }
  sv_s[tid] = sa_v[tid];
  cv_s[tid] = ca_v[tid];
  __syncthreads();

  // phase 2: concept scores (2 concepts x 32 keys)
  if (tid < 64) {
    int c = tid >> 5, k = tid & 31;
    const float* cqr = cq + (c * 8 + (n >> 5)) * 256;
    float acc = 0.0f;
    for (int h = 0; h < 256; ++h)
      acc += tanh_fast(cqr[h] + (float)bufA[k * 264 + h]) * cv_s[h];
    float sc = acc + ca_vb[0];
    sbc[c * 33 + k] = (sl > (k << 2)) ? sc : -1e9f;
  }
  __syncthreads();

  // phase 3: load qp/kp (all threads) + concept softmax (2 threads)
#pragma unroll
  for (int rr = 0; rr < 4; ++rr) {
    int q = tid + (rr << 8);
    int k = q >> 5, c8 = (q & 31) << 3;
    *(uint4*)&bufB[k * 264 + c8] = *(const uint4*)&qkc[n * 24576 + k * 768 + c8];        // qp
    *(uint4*)&bufA[k * 264 + c8] = *(const uint4*)&qkc[n * 24576 + k * 768 + 256 + c8];  // kp
  }
  if (tid < 2) {
    float* row = &sbc[tid * 33];
    float mx = -1e30f;
    for (int k = 0; k < 32; ++k) mx = fmaxf(mx, row[k]);
    float sum = 0.0f;
    for (int k = 0; k < 32; ++k) { float e = __expf(row[k] - mx); row[k] = e; sum += e; }
    float inv = 1.0f / sum;
    for (int k = 0; k < 32; ++k) row[k] *= inv;
  }
  __syncthreads();

  // phase 4a: concept result + write tmp2/c1/c2 into ar
  {
    int col = tid;
    float rr0 = 0.0f, rr1 = 0.0f;
    for (int k = 0; k < 32; ++k) {
      float tv = (float)t2[k * 264 + col];
      rr0 += sbc[k] * tv;
      rr1 += sbc[33 + k] * tv;
    }
    bf16 b0 = (bf16)rr0, b1 = (bf16)rr1;
    bf16* arn = ar + n * 32768;
    for (int q = 0; q < 32; ++q) {
      arn[q * 1024 + col]       = t2[q * 264 + col];
      arn[q * 1024 + 512 + col] = b0;
      arn[q * 1024 + 768 + col] = b1;
    }
  }
  // phase 4b: self-attention scores (4 (q,k) pairs per thread)
  {
    float svb = sa_vb[0];
#pragma unroll
    for (int rr = 0; rr < 4; ++rr) {
      int id = tid + (rr << 8);
      int q = id >> 5, k = id & 31;
      float acc = 0.0f;
      for (int h = 0; h < 256; ++h)
        acc += tanh_fast((float)bufB[q * 264 + h] + (float)bufA[k * 264 + h]) * sv_s[h];
      float sc = acc + svb;
      sbs[q * 33 + k] = (sl > (k << 2)) ? sc : -1e9f;
    }
  }
  __syncthreads();

  // phase 5: self softmax (32 rows)
  if (tid < 32) {
    float* row = &sbs[tid * 33];
    float mx = -1e30f;
    for (int k = 0; k < 32; ++k) mx = fmaxf(mx, row[k]);
    float sum = 0.0f;
    for (int k = 0; k < 32; ++k) { float e = __expf(row[k] - mx); row[k] = e; sum += e; }
    float inv = 1.0f / sum;
    for (int k = 0; k < 32; ++k) row[k] *= inv;
  }
  __syncthreads();

  // phase 6: self_res -> ar[256:512)
  {
    int col = tid;
    bf16* arn = ar + n * 32768;
    for (int q = 0; q < 32; ++q) {
      float acc = 0.0f;
      for (int k = 0; k < 32; ++k)
        acc += sbs[q * 33 + k] * (float)t2[k * 264 + col];
      arn[q * 1024 + 256 + col] = (bf16)acc;
    }
  }
}

// ---------------- final score ----------------
__global__ __launch_bounds__(256) void kscore(
    const bf16* __restrict__ sim1, const float* __restrict__ uu,
    const float* __restrict__ mlp_b, float* __restrict__ out)
{
  int row = blockIdx.x * 256 + threadIdx.x;   // [0, 32768)
  int b = row >> 12;
  const float* u0 = uu + b * 128;
  const float* u1 = uu + 1024 + b * 128;
  const bf16* sr = sim1 + row * 128;
  float d0 = 0.0f, d1 = 0.0f;
  for (int mm = 0; mm < 128; mm += 8) {
    bf16x8 v = *(const bf16x8*)&sr[mm];
#pragma unroll
    for (int t = 0; t < 8; ++t) {
      float sv = (float)v[t];
      d0 += sv * u0[mm + t];
      d1 += sv * u1[mm + t];
    }
  }
  float bb = mlp_b[0];
  out[row]         = 1.0f / (1.0f + __expf(-(d0 + bb)));
  out[32768 + row] = 1.0f / (1.0f + __expf(-(d1 + bb)));
}

// ---------------- launch ----------------
extern "C" void kernel_launch(void* const* d_in, const int* in_sizes, int n_in,
                              void* d_out, int out_size, void* d_ws, size_t ws_size,
                              hipStream_t stream) {
  const float* batch    = (const float*)d_in[0];
  const float* concept1 = (const float*)d_in[1];
  const float* concept2 = (const float*)d_in[2];
  const int*   seg      = (const int*)d_in[3];
  const float* conv1_w  = (const float*)d_in[4];
  const float* conv1_b  = (const float*)d_in[5];
  const float* conv2_w  = (const float*)d_in[6];
  const float* conv2_b  = (const float*)d_in[7];
  const float* sa_wq    = (const float*)d_in[8];
  const float* sa_bq    = (const float*)d_in[9];
  const float* sa_wk    = (const float*)d_in[10];
  const float* sa_bk    = (const float*)d_in[11];
  const float* sa_v     = (const float*)d_in[12];
  const float* sa_vb    = (const float*)d_in[13];
  const float* ca_wq    = (const float*)d_in[14];
  const float* ca_bq    = (const float*)d_in[15];
  const float* ca_wk    = (const float*)d_in[16];
  const float* ca_bk    = (const float*)d_in[17];
  const float* ca_v     = (const float*)d_in[18];
  const float* ca_vb    = (const float*)d_in[19];
  const float* dc1_w    = (const float*)d_in[20];
  const float* dc1_b    = (const float*)d_in[21];
  const float* dc2_w    = (const float*)d_in[22];
  const float* dc2_b    = (const float*)d_in[23];
  const float* sim1_w   = (const float*)d_in[24];
  const float* sim2_w   = (const float*)d_in[25];
  const float* mlp_w    = (const float*)d_in[26];
  const float* mlp_b    = (const float*)d_in[27];

  char* ws = (char*)d_ws;
  // Workspace layout (102.2 MB; lifetime-based aliasing):
  //  [0,67.1M)   batch_bf16 (dead after conv1) -> qkc/ar/d1/rbuf/sim1b
  //  [67.1M,83.9M) t1 | [83.9M,88.1M) tmp2 | [88.1M,...) weights/bias/cq/uu
  bf16* bb16  = (bf16*)(ws + 0);
  bf16* qkcb  = (bf16*)(ws + 0);
  bf16* arb   = (bf16*)(ws + 12582912);
  bf16* d1    = (bf16*)(ws + 29360128);
  bf16* rbuf  = (bf16*)(ws + 46137344);
  bf16* sim1b = (bf16*)(ws + 54525952);
  bf16* t1    = (bf16*)(ws + 67108864);
  bf16* tmp2b = (bf16*)(ws + 83886080);
  bf16* Bt1   = (bf16*)(ws + 88080384);
  bf16* Bt2   = (bf16*)(ws + 93323264);
  bf16* Bqkc  = (bf16*)(ws + 94633984);
  bf16* Btd1  = (bf16*)(ws + 95027200);
  bf16* Btd2  = (bf16*)(ws + 101318656);
  bf16* Bts1  = (bf16*)(ws + 102105088);
  float* biasall = (float*)(ws + 102137856);
  float* cqb  = (float*)(ws + 102149632);
  float* uub  = (float*)(ws + 102166016);
  const bf16* zp = (const bf16*)(biasall + 2816);  // 128 f32 zeros = 256 bf16 zeros
  float* outp = (float*)d_out;

  // single fused prep (weights re-layout + biases + cq/uu)
  prep_all<<<27492, 256, 0, stream>>>(
      conv1_w, conv2_w, sa_wq, sa_wk, ca_wk, dc1_w, dc2_w, sim1_w,
      conv1_b, conv2_b, sa_bq, sa_bk, ca_bk, dc1_b, dc2_b,
      concept1, concept2, ca_wq, ca_bq, sim2_w, mlp_w,
      Bt1, Bt2, Bqkc, Btd1, Btd2, Bts1, biasall, cqb, uub);

  // batch fp32 -> bf16
  kcvt<<<16384, 256, 0, stream>>>(batch, bb16);

  // conv1 + pool: 5 taps x CI=1024 -> t1 [256][64][512]
  gemm_tap<true><<<dim3(4, 256), 256, 0, stream>>>(
      bb16, Bt1, biasall + 0, t1, zp, 131072, 7, 10, -2, 5, 32, 5120, 512, 32768);

  // conv2 + pool: 5 taps x CI=512 -> tmp2 [256][32][256]
  gemm_tap<true><<<dim3(2, 128), 256, 0, stream>>>(
      t1, Bt2, biasall + 512, tmp2b, zp, 32768, 6, 9, -2, 5, 16, 2560, 256, 8192);

  // fused q/k/ck projection: 1 tap x CI=256 -> qkc [256][32][768]
  gemm_tap<false><<<dim3(6, 64), 256, 0, stream>>>(
      tmp2b, Bqkc, biasall + 768, qkcb, zp, 8192, 5, 8, 0, 1, 8, 256, 768, 24576);

  // attention -> ar [256][32][1024]
  kattn<<<256, 256, 0, stream>>>(tmp2b, qkcb, sa_v, sa_vb, ca_v, ca_vb, cqb, seg, arb);

  // deconv1: 3 taps x CI=1024 -> d1 [256][64][1024] (parity-interleaved)
  gemm_tap<false><<<dim3(8, 64), 256, 0, stream>>>(
      arb, Btd1, biasall + 1536, d1, zp, 32768, 5, 10, -1, 3, 32, 3072, 1024, 32768);

  // deconv2: 3 taps x CI=512 -> rbuf [256][64][256] (parity-interleaved)
  gemm_tap<false><<<dim3(2, 128), 256, 0, stream>>>(
      d1, Btd2, biasall + 2560, rbuf, zp, 32768, 6, 9, -1, 3, 16, 1536, 256, 16384);

  // sim1 = r @ sim1_w: 1 tap x CI=128 -> sim1b [32768][128]
  gemm_tap<false><<<dim3(1, 256), 256, 0, stream>>>(
      rbuf, Bts1, biasall + 2816, sim1b, zp, 16384, 7, 7, 0, 1, 4, 128, 128, 16384);

  // final scores (fp32 out)
  kscore<<<128, 256, 0, stream>>>(sim1b, uub, mlp_b, outp);
}

// Round 5
// 757.260 us; speedup vs baseline: 1.3957x; 1.1070x over previous
//
#include <hip/hip_runtime.h>
#include <cstdint>

typedef __bf16 bf16;
typedef __bf16 bf16x8 __attribute__((ext_vector_type(8)));
typedef float f32x4 __attribute__((ext_vector_type(4)));

// ---------------- helpers ----------------
__device__ __forceinline__ void gload_lds16(const void* g, void* l) {
  __builtin_amdgcn_global_load_lds(
      (const __attribute__((address_space(1))) unsigned int*)g,
      (__attribute__((address_space(3))) unsigned int*)l, 16, 0, 0);
}

__device__ __forceinline__ float tanh_fast(float x) {
  float ax = fabsf(x);
  float e = __expf(ax + ax);
  float t = 1.0f - 2.0f / (e + 1.0f);
  return x < 0.0f ? -t : t;
}

// ---------------- shifted-tap GEMM, cb-outer/tap-inner, 64k per barrier ----
// C[m, co] = sum_{cb,tap,cl} A[n][p+tap+shift0][cb*cbCI+cl] * Bt[co][(cb*ntaps+tap)*cbCI+cl]
// m = n*P + p (P=1<<logP). A unpadded bf16 [n][P][CI]; out-of-range rows -> zero
// page zp (global_load_lds takes per-lane source addresses). K-order is
// ci-block(256) OUTER, tap INNER: tap re-reads of A have ~70KB reuse distance
// -> L2-resident (vs 8MB+ with tap-outer). Two 32-k buffer pairs per barrier
// (32KB LDS): 32 MFMA per __syncthreads pair, half the vmcnt drains.
// Grid: blockIdx.x = m-tile (fast dim -> same-m co-blocks land on same XCD,
// gridDim.x % 8 == 0), blockIdx.y = co-tile.
// POOL: max over adjacent row pairs -> out position p>>1 (fused maxpool2).
template<bool POOL>
__global__ __launch_bounds__(256) void gemm_tap(
    const bf16* __restrict__ A, const bf16* __restrict__ Bt,
    const float* __restrict__ bias, bf16* __restrict__ Out,
    const bf16* __restrict__ zp,
    int snA, int logP, int logCI, int shift0, int ntaps, int cbCount,
    int cbCI, int pairs, int Ktot, int COt, int snO)
{
  __shared__ __align__(16) bf16 Ab[2][4096];
  __shared__ __align__(16) bf16 Bb[2][4096];
  const int tid  = threadIdx.x;
  const int wave = tid >> 6, lane = tid & 63;
  const int wr = wave >> 1, wc = wave & 1;
  const int m0  = blockIdx.x << 7;       // m fast -> XCD shares A across co
  const int co0 = blockIdx.y << 7;
  const int P     = 1 << logP;
  const int Pmask = P - 1;
  const int CI    = 1 << logCI;
  f32x4 acc[4][4] = {};

  // staging lane map: rowL = global row (0..63, +64 rep1), kg = 16B segment;
  // XOR k-group swizzle (consistent with read side; f(row)=f(row&15) since
  // 16|rowbase and 20*b%4==0)
  const int rowL = tid >> 2;
  const int kg   = tid & 3;
  const int fOff = ((kg ^ ((rowL + (rowL >> 2)) & 3)) << 3);
  bf16* dA0r0 = &Ab[0][wave * 512];
  bf16* dA0r1 = &Ab[0][2048 + wave * 512];
  bf16* dA1r0 = &Ab[1][wave * 512];
  bf16* dA1r1 = &Ab[1][2048 + wave * 512];
  bf16* dB0r0 = &Bb[0][wave * 512];
  bf16* dB0r1 = &Bb[0][2048 + wave * 512];
  bf16* dB1r0 = &Bb[1][wave * 512];
  bf16* dB1r1 = &Bb[1][2048 + wave * 512];

  // A row decompose (per rep, tap-independent)
  const int mA0 = m0 + rowL,      nA0 = mA0 >> logP, pA0v = mA0 & Pmask;
  const int mA1 = m0 + rowL + 64, nA1 = mA1 >> logP, pA1v = mA1 & Pmask;
  const bf16* baseA0 = A + nA0 * snA + fOff;
  const bf16* baseA1 = A + nA1 * snA + fOff;
  const bf16* baseB0 = Bt + (co0 + rowL) * Ktot + fOff;
  const bf16* baseB1 = Bt + (co0 + rowL + 64) * Ktot + fOff;
  const bf16* zsrc = zp + fOff;

  // fragment read offsets (match staging swizzle; <=2-way banks = free)
  const int frow  = lane & 15;
  const int rdOff = (((lane >> 4) ^ ((frow + (frow >> 2)) & 3)) << 3);

  for (int cb = 0; cb < cbCount; ++cb) {
    for (int tap = 0; tap < ntaps; ++tap) {
      const int sh = tap + shift0;
      const int rA0 = pA0v + sh, rA1 = pA1v + sh;
      const bool v0 = (unsigned)rA0 < (unsigned)P;
      const bool v1 = (unsigned)rA1 < (unsigned)P;
      const bf16* pa0 = v0 ? (baseA0 + rA0 * CI + cb * cbCI) : zsrc;
      const bf16* pa1 = v1 ? (baseA1 + rA1 * CI + cb * cbCI) : zsrc;
      const bf16* pb0 = baseB0 + (cb * ntaps + tap) * cbCI;
      const bf16* pb1 = baseB1 + (cb * ntaps + tap) * cbCI;

      for (int kc = 0; kc < pairs; ++kc) {
        gload_lds16(pa0,      dA0r0);
        gload_lds16(pa0 + 32, dA1r0);
        gload_lds16(pa1,      dA0r1);
        gload_lds16(pa1 + 32, dA1r1);
        gload_lds16(pb0,      dB0r0);
        gload_lds16(pb0 + 32, dB1r0);
        gload_lds16(pb1,      dB0r1);
        gload_lds16(pb1 + 32, dB1r1);
        if (v0) pa0 += 64;
        if (v1) pa1 += 64;
        pb0 += 64; pb1 += 64;
        __syncthreads();
#pragma unroll
        for (int h = 0; h < 2; ++h) {
          bf16x8 af[4], bg[4];
#pragma unroll
          for (int i = 0; i < 4; ++i) {
            af[i] = *(const bf16x8*)&Ab[h][((wr << 6) + (i << 4) + frow) * 32 + rdOff];
            bg[i] = *(const bf16x8*)&Bb[h][((wc << 6) + (i << 4) + frow) * 32 + rdOff];
          }
#pragma unroll
          for (int i = 0; i < 4; ++i)
#pragma unroll
            for (int j = 0; j < 4; ++j)
              acc[i][j] = __builtin_amdgcn_mfma_f32_16x16x32_bf16(af[i], bg[j], acc[i][j], 0, 0, 0);
        }
        __syncthreads();
      }
    }
  }

  // epilogue: C/D layout col=lane&15, row=(lane>>4)*4+reg  [m89-verified]
  const int colL = lane & 15;
  const int rq   = (lane >> 4) << 2;
#pragma unroll
  for (int i = 0; i < 4; ++i) {
    int m = m0 + (wr << 6) + (i << 4) + rq;
    int n = m >> logP, p = m & Pmask;
#pragma unroll
    for (int j = 0; j < 4; ++j) {
      int gco = co0 + (wc << 6) + (j << 4) + colL;
      float bv = bias[gco];
      if (POOL) {
        float v0 = fmaxf(acc[i][j][0], acc[i][j][1]) + bv;
        float v1 = fmaxf(acc[i][j][2], acc[i][j][3]) + bv;
        bf16* o = Out + n * snO + (p >> 1) * COt + gco;
        o[0]   = (bf16)v0;
        o[COt] = (bf16)v1;
      } else {
#pragma unroll
        for (int r = 0; r < 4; ++r)
          Out[n * snO + (p + r) * COt + gco] = (bf16)(acc[i][j][r] + bv);
      }
    }
  }
}

// ---------------- batch fp32 -> bf16 ----------------
__global__ void kcvt(const float* __restrict__ src, bf16* __restrict__ dst) {
  int idx = (blockIdx.x * 256 + threadIdx.x) * 8;     // 33554432 elems
  float4 a = *(const float4*)&src[idx];
  float4 b = *(const float4*)&src[idx + 4];
  bf16x8 v;
  v[0] = (bf16)a.x; v[1] = (bf16)a.y; v[2] = (bf16)a.z; v[3] = (bf16)a.w;
  v[4] = (bf16)b.x; v[5] = (bf16)b.y; v[6] = (bf16)b.z; v[7] = (bf16)b.w;
  *(bf16x8*)&dst[idx] = v;
}

// ---------------- fused prep: all weight re-layouts + biases + cq/uu --------
// Conv/deconv Bt layouts are now [co][cb][tap][ci256] (cb-outer, tap-inner).
// idx ranges: [0,3072) bias | [3072,2624512) Bt1 | [2624512,3279872) Bt2 |
// [3279872,3476480) Bqkc | [3476480,6622208) Btd1 | [6622208,7015424) Btd2 |
// [7015424,7031808) Bts1. Blocks >= 27468 do cq (16 blocks) + uu (8 blocks).
__global__ __launch_bounds__(256) void prep_all(
    const float* __restrict__ conv1_w, const float* __restrict__ conv2_w,
    const float* __restrict__ sa_wq, const float* __restrict__ sa_wk,
    const float* __restrict__ ca_wk, const float* __restrict__ dc1_w,
    const float* __restrict__ dc2_w, const float* __restrict__ sim1_w,
    const float* __restrict__ c1b, const float* __restrict__ c2b,
    const float* __restrict__ sabq, const float* __restrict__ sabk,
    const float* __restrict__ cabk, const float* __restrict__ d1b,
    const float* __restrict__ d2b,
    const float* __restrict__ c1, const float* __restrict__ c2,
    const float* __restrict__ ca_wq, const float* __restrict__ ca_bq,
    const float* __restrict__ sim2_w, const float* __restrict__ mlp_w,
    bf16* __restrict__ Bt1, bf16* __restrict__ Bt2, bf16* __restrict__ Bqkc,
    bf16* __restrict__ Btd1, bf16* __restrict__ Btd2, bf16* __restrict__ Bts1,
    float* __restrict__ bias, float* __restrict__ cq, float* __restrict__ uu)
{
  const int blk = blockIdx.x;
  if (blk < 27468) {
    int idx = blk * 256 + threadIdx.x;
    if (idx < 3072) {
      // biases -> f32: [0,512) c1 | [512,768) c2 | [768,1536) qkc |
      // [1536,2560) d1 dup | [2560,2816) d2 dup | [2816,2944) zeros
      if (idx < 2944) {
        float v;
        if (idx < 512)       v = c1b[idx];
        else if (idx < 768)  v = c2b[idx - 512];
        else if (idx < 1024) v = sabq[idx - 768];
        else if (idx < 1280) v = sabk[idx - 1024];
        else if (idx < 1536) v = cabk[idx - 1280];
        else if (idx < 2560) v = d1b[(idx - 1536) & 511];
        else if (idx < 2816) v = d2b[(idx - 2560) & 127];
        else                 v = 0.0f;
        bias[idx] = v;
      }
    } else if (idx < 2624512) {
      // Bt1[co][cb4][tap5][cl256] = conv1_w[co][cb*256+cl][tap]
      int i = idx - 3072;
      int co = i / 5120, r = i - co * 5120;
      int cb = r / 1280, r2 = r - cb * 1280;
      int tap = r2 >> 8, cl = r2 & 255;
      Bt1[i] = (bf16)conv1_w[co * 5120 + (cb * 256 + cl) * 5 + tap];
    } else if (idx < 3279872) {
      // Bt2[co][cb2][tap5][cl256]
      int i = idx - 2624512;
      int co = i / 2560, r = i - co * 2560;
      int cb = r / 1280, r2 = r - cb * 1280;
      int tap = r2 >> 8, cl = r2 & 255;
      Bt2[i] = (bf16)conv2_w[co * 2560 + (cb * 256 + cl) * 5 + tap];
    } else if (idx < 3476480) {
      // Bqkc[co][ci]: co<256 sa_wq | <512 sa_wk | <768 ca_wk ([in][out] stored)
      int i = idx - 3279872;
      int co = i >> 8, ci = i & 255;
      float v;
      if (co < 256)      v = sa_wq[ci * 256 + co];
      else if (co < 512) v = sa_wk[ci * 256 + (co - 256)];
      else               v = ca_wk[ci * 256 + (co - 512)];
      Bqkc[i] = (bf16)v;
    } else if (idx < 6622208) {
      // Btd1[co][cb4][tap3][cl256]; parity fold:
      // even co: tap1->ki1, tap0->ki3; odd co: tap2->ki0, tap1->ki2
      int i = idx - 3476480;
      int co = i / 3072, r = i - co * 3072;
      int cb = r / 768, r2 = r - cb * 768;
      int tap = r2 >> 8, cl = r2 & 255;
      int ci = cb * 256 + cl;
      int par = co >> 9, c = co & 511;
      int ki = -1;
      if (par == 0) { if (tap == 1) ki = 1; else if (tap == 0) ki = 3; }
      else          { if (tap == 2) ki = 0; else if (tap == 1) ki = 2; }
      Btd1[i] = (ki >= 0) ? (bf16)dc1_w[ci * 2048 + c * 4 + ki] : (bf16)0.0f;
    } else if (idx < 7015424) {
      // Btd2[co][cb2][tap3][cl256]
      int i = idx - 6622208;
      int co = i / 1536, r = i - co * 1536;
      int cb = r / 768, r2 = r - cb * 768;
      int tap = r2 >> 8, cl = r2 & 255;
      int ci = cb * 256 + cl;
      int par = co >> 7, c = co & 127;
      int ki = -1;
      if (par == 0) { if (tap == 1) ki = 1; else if (tap == 0) ki = 3; }
      else          { if (tap == 2) ki = 0; else if (tap == 1) ki = 2; }
      Btd2[i] = (ki >= 0) ? (bf16)dc2_w[ci * 512 + c * 4 + ki] : (bf16)0.0f;
    } else {
      int i = idx - 7015424;
      int co = i >> 7, ci = i & 127;
      Bts1[i] = (bf16)sim1_w[ci * 128 + co];
    }
  } else {
    int sub = blk - 27468;
    if (sub < 16) {
      // cq[c][b][h] = concept_c[b] @ ca_wq + ca_bq   (4096 outs)
      int o = sub * 256 + threadIdx.x;
      int c = o >> 11, b = (o >> 8) & 7, h = o & 255;
      const float* cc = (c ? c2 : c1) + b * 300;
      float acc = ca_bq[h];
      for (int j = 0; j < 300; ++j)
        acc += cc[j] * ca_wq[j * 256 + h];
      cq[o] = acc;
    } else {
      // uu[c][b][m] = (concept_c[b] @ sim2_w) * mlp_w   (2048 outs)
      int o = (sub - 16) * 256 + threadIdx.x;
      int c = o >> 10, b = (o >> 7) & 7, m = o & 127;
      const float* cc = (c ? c2 : c1) + b * 300;
      float acc = 0.0f;
      for (int j = 0; j < 300; ++j)
        acc += cc[j] * sim2_w[j * 128 + m];
      uu[o] = acc * mlp_w[m];
    }
  }
}

// ---------------- fused additive attention (one block per n) ----------------
// builds ar[n][q][0:256)=tmp2, [256:512)=self_res, [512:768)=c1_res, [768:1024)=c2_res
__global__ __launch_bounds__(256) void kattn(
    const bf16* __restrict__ tmp2, const bf16* __restrict__ qkc,
    const float* __restrict__ sa_v, const float* __restrict__ sa_vb,
    const float* __restrict__ ca_v, const float* __restrict__ ca_vb,
    const float* __restrict__ cq, const int* __restrict__ seg,
    bf16* __restrict__ ar)
{
  const int n = blockIdx.x, tid = threadIdx.x;
  __shared__ __align__(16) bf16 t2[32 * 264];
  __shared__ __align__(16) bf16 bufA[32 * 264];
  __shared__ __align__(16) bf16 bufB[32 * 264];
  __shared__ float sv_s[256], cv_s[256];
  __shared__ float sbc[66];
  __shared__ float sbs[32 * 33];
  const int sl = seg[n];

  // phase 1: load tmp2 + ckp + score vectors
#pragma unroll
  for (int rr = 0; rr < 4; ++rr) {
    int q = tid + (rr << 8);
    int k = q >> 5, c8 = (q & 31) << 3;
    *(uint4*)&t2[k * 264 + c8]   = *(const uint4*)&tmp2[n * 8192 + k * 256 + c8];
    *(uint4*)&bufA[k * 264 + c8] = *(const uint4*)&qkc[n * 24576 + k * 768 + 512 + c8];
  }
  sv_s[tid] = sa_v[tid];
  cv_s[tid] = ca_v[tid];
  __syncthreads();

  // phase 2: concept scores (2 concepts x 32 keys)
  if (tid < 64) {
    int c = tid >> 5, k = tid & 31;
    const float* cqr = cq + (c * 8 + (n >> 5)) * 256;
    float acc = 0.0f;
    for (int h = 0; h < 256; ++h)
      acc += tanh_fast(cqr[h] + (float)bufA[k * 264 + h]) * cv_s[h];
    float sc = acc + ca_vb[0];
    sbc[c * 33 + k] = (sl > (k << 2)) ? sc : -1e9f;
  }
  __syncthreads();

  // phase 3: load qp/kp (all threads) + concept softmax (2 threads)
#pragma unroll
  for (int rr = 0; rr < 4; ++rr) {
    int q = tid + (rr << 8);
    int k = q >> 5, c8 = (q & 31) << 3;
    *(uint4*)&bufB[k * 264 + c8] = *(const uint4*)&qkc[n * 24576 + k * 768 + c8];        // qp
    *(uint4*)&bufA[k * 264 + c8] = *(const uint4*)&qkc[n * 24576 + k * 768 + 256 + c8];  // kp
  }
  if (tid < 2) {
    float* row = &sbc[tid * 33];
    float mx = -1e30f;
    for (int k = 0; k < 32; ++k) mx = fmaxf(mx, row[k]);
    float sum = 0.0f;
    for (int k = 0; k < 32; ++k) { float e = __expf(row[k] - mx); row[k] = e; sum += e; }
    float inv = 1.0f / sum;
    for (int k = 0; k < 32; ++k) row[k] *= inv;
  }
  __syncthreads();

  // phase 4a: concept result + write tmp2/c1/c2 into ar
  {
    int col = tid;
    float rr0 = 0.0f, rr1 = 0.0f;
    for (int k = 0; k < 32; ++k) {
      float tv = (float)t2[k * 264 + col];
      rr0 += sbc[k] * tv;
      rr1 += sbc[33 + k] * tv;
    }
    bf16 b0 = (bf16)rr0, b1 = (bf16)rr1;
    bf16* arn = ar + n * 32768;
    for (int q = 0; q < 32; ++q) {
      arn[q * 1024 + col]       = t2[q * 264 + col];
      arn[q * 1024 + 512 + col] = b0;
      arn[q * 1024 + 768 + col] = b1;
    }
  }
  // phase 4b: self-attention scores (4 (q,k) pairs per thread)
  {
    float svb = sa_vb[0];
#pragma unroll
    for (int rr = 0; rr < 4; ++rr) {
      int id = tid + (rr << 8);
      int q = id >> 5, k = id & 31;
      float acc = 0.0f;
      for (int h = 0; h < 256; ++h)
        acc += tanh_fast((float)bufB[q * 264 + h] + (float)bufA[k * 264 + h]) * sv_s[h];
      float sc = acc + svb;
      sbs[q * 33 + k] = (sl > (k << 2)) ? sc : -1e9f;
    }
  }
  __syncthreads();

  // phase 5: self softmax (32 rows)
  if (tid < 32) {
    float* row = &sbs[tid * 33];
    float mx = -1e30f;
    for (int k = 0; k < 32; ++k) mx = fmaxf(mx, row[k]);
    float sum = 0.0f;
    for (int k = 0; k < 32; ++k) { float e = __expf(row[k] - mx); row[k] = e; sum += e; }
    float inv = 1.0f / sum;
    for (int k = 0; k < 32; ++k) row[k] *= inv;
  }
  __syncthreads();

  // phase 6: self_res -> ar[256:512)
  {
    int col = tid;
    bf16* arn = ar + n * 32768;
    for (int q = 0; q < 32; ++q) {
      float acc = 0.0f;
      for (int k = 0; k < 32; ++k)
        acc += sbs[q * 33 + k] * (float)t2[k * 264 + col];
      arn[q * 1024 + 256 + col] = (bf16)acc;
    }
  }
}

// ---------------- final score ----------------
__global__ __launch_bounds__(256) void kscore(
    const bf16* __restrict__ sim1, const float* __restrict__ uu,
    const float* __restrict__ mlp_b, float* __restrict__ out)
{
  int row = blockIdx.x * 256 + threadIdx.x;   // [0, 32768)
  int b = row >> 12;
  const float* u0 = uu + b * 128;
  const float* u1 = uu + 1024 + b * 128;
  const bf16* sr = sim1 + row * 128;
  float d0 = 0.0f, d1 = 0.0f;
  for (int mm = 0; mm < 128; mm += 8) {
    bf16x8 v = *(const bf16x8*)&sr[mm];
#pragma unroll
    for (int t = 0; t < 8; ++t) {
      float sv = (float)v[t];
      d0 += sv * u0[mm + t];
      d1 += sv * u1[mm + t];
    }
  }
  float bb = mlp_b[0];
  out[row]         = 1.0f / (1.0f + __expf(-(d0 + bb)));
  out[32768 + row] = 1.0f / (1.0f + __expf(-(d1 + bb)));
}

// ---------------- launch ----------------
extern "C" void kernel_launch(void* const* d_in, const int* in_sizes, int n_in,
                              void* d_out, int out_size, void* d_ws, size_t ws_size,
                              hipStream_t stream) {
  const float* batch    = (const float*)d_in[0];
  const float* concept1 = (const float*)d_in[1];
  const float* concept2 = (const float*)d_in[2];
  const int*   seg      = (const int*)d_in[3];
  const float* conv1_w  = (const float*)d_in[4];
  const float* conv1_b  = (const float*)d_in[5];
  const float* conv2_w  = (const float*)d_in[6];
  const float* conv2_b  = (const float*)d_in[7];
  const float* sa_wq    = (const float*)d_in[8];
  const float* sa_bq    = (const float*)d_in[9];
  const float* sa_wk    = (const float*)d_in[10];
  const float* sa_bk    = (const float*)d_in[11];
  const float* sa_v     = (const float*)d_in[12];
  const float* sa_vb    = (const float*)d_in[13];
  const float* ca_wq    = (const float*)d_in[14];
  const float* ca_bq    = (const float*)d_in[15];
  const float* ca_wk    = (const float*)d_in[16];
  const float* ca_bk    = (const float*)d_in[17];
  const float* ca_v     = (const float*)d_in[18];
  const float* ca_vb    = (const float*)d_in[19];
  const float* dc1_w    = (const float*)d_in[20];
  const float* dc1_b    = (const float*)d_in[21];
  const float* dc2_w    = (const float*)d_in[22];
  const float* dc2_b    = (const float*)d_in[23];
  const float* sim1_w   = (const float*)d_in[24];
  const float* sim2_w   = (const float*)d_in[25];
  const float* mlp_w    = (const float*)d_in[26];
  const float* mlp_b    = (const float*)d_in[27];

  char* ws = (char*)d_ws;
  // Workspace layout (102.2 MB; lifetime-based aliasing):
  //  [0,67.1M)   batch_bf16 (dead after conv1) -> qkc/ar/d1/rbuf/sim1b
  //  [67.1M,83.9M) t1 | [83.9M,88.1M) tmp2 | [88.1M,...) weights/bias/cq/uu
  bf16* bb16  = (bf16*)(ws + 0);
  bf16* qkcb  = (bf16*)(ws + 0);
  bf16* arb   = (bf16*)(ws + 12582912);
  bf16* d1    = (bf16*)(ws + 29360128);
  bf16* rbuf  = (bf16*)(ws + 46137344);
  bf16* sim1b = (bf16*)(ws + 54525952);
  bf16* t1    = (bf16*)(ws + 67108864);
  bf16* tmp2b = (bf16*)(ws + 83886080);
  bf16* Bt1   = (bf16*)(ws + 88080384);
  bf16* Bt2   = (bf16*)(ws + 93323264);
  bf16* Bqkc  = (bf16*)(ws + 94633984);
  bf16* Btd1  = (bf16*)(ws + 95027200);
  bf16* Btd2  = (bf16*)(ws + 101318656);
  bf16* Bts1  = (bf16*)(ws + 102105088);
  float* biasall = (float*)(ws + 102137856);
  float* cqb  = (float*)(ws + 102149632);
  float* uub  = (float*)(ws + 102166016);
  const bf16* zp = (const bf16*)(biasall + 2816);  // 128 f32 zeros = 256 bf16 zeros
  float* outp = (float*)d_out;

  // single fused prep (weights re-layout + biases + cq/uu)
  prep_all<<<27492, 256, 0, stream>>>(
      conv1_w, conv2_w, sa_wq, sa_wk, ca_wk, dc1_w, dc2_w, sim1_w,
      conv1_b, conv2_b, sa_bq, sa_bk, ca_bk, dc1_b, dc2_b,
      concept1, concept2, ca_wq, ca_bq, sim2_w, mlp_w,
      Bt1, Bt2, Bqkc, Btd1, Btd2, Bts1, biasall, cqb, uub);

  // batch fp32 -> bf16
  kcvt<<<16384, 256, 0, stream>>>(batch, bb16);

  // conv1 + pool: cb4 x tap5 x 256ci -> t1 [256][64][512]
  gemm_tap<true><<<dim3(256, 4), 256, 0, stream>>>(
      bb16, Bt1, biasall + 0, t1, zp, 131072, 7, 10, -2, 5, 4, 256, 4, 5120, 512, 32768);

  // conv2 + pool: cb2 x tap5 x 256ci -> tmp2 [256][32][256]
  gemm_tap<true><<<dim3(128, 2), 256, 0, stream>>>(
      t1, Bt2, biasall + 512, tmp2b, zp, 32768, 6, 9, -2, 5, 2, 256, 4, 2560, 256, 8192);

  // fused q/k/ck projection: cb1 x tap1 x 256ci -> qkc [256][32][768]
  gemm_tap<false><<<dim3(64, 6), 256, 0, stream>>>(
      tmp2b, Bqkc, biasall + 768, qkcb, zp, 8192, 5, 8, 0, 1, 1, 256, 4, 256, 768, 24576);

  // attention -> ar [256][32][1024]
  kattn<<<256, 256, 0, stream>>>(tmp2b, qkcb, sa_v, sa_vb, ca_v, ca_vb, cqb, seg, arb);

  // deconv1: cb4 x tap3 x 256ci -> d1 [256][64][1024] (parity-interleaved)
  gemm_tap<false><<<dim3(64, 8), 256, 0, stream>>>(
      arb, Btd1, biasall + 1536, d1, zp, 32768, 5, 10, -1, 3, 4, 256, 4, 3072, 1024, 32768);

  // deconv2: cb2 x tap3 x 256ci -> rbuf [256][64][256] (parity-interleaved)
  gemm_tap<false><<<dim3(128, 2), 256, 0, stream>>>(
      d1, Btd2, biasall + 2560, rbuf, zp, 32768, 6, 9, -1, 3, 2, 256, 4, 1536, 256, 16384);

  // sim1 = r @ sim1_w: cb1 x tap1 x 128ci (2 pairs) -> sim1b [32768][128]
  gemm_tap<false><<<dim3(256, 1), 256, 0, stream>>>(
      rbuf, Bts1, biasall + 2816, sim1b, zp, 16384, 7, 7, 0, 1, 1, 128, 2, 128, 128, 16384);

  // final scores (fp32 out)
  kscore<<<128, 256, 0, stream>>>(sim1b, uub, mlp_b, outp);
}

// Round 6
// 714.842 us; speedup vs baseline: 1.4785x; 1.0593x over previous
//
#include <hip/hip_runtime.h>
#include <cstdint>

typedef __bf16 bf16;
typedef __bf16 bf16x8 __attribute__((ext_vector_type(8)));
typedef float f32x4 __attribute__((ext_vector_type(4)));

// ---------------- helpers ----------------
__device__ __forceinline__ void gload_lds16(const void* g, void* l) {
  __builtin_amdgcn_global_load_lds(
      (const __attribute__((address_space(1))) unsigned int*)g,
      (__attribute__((address_space(3))) unsigned int*)l, 16, 0, 0);
}

__device__ __forceinline__ float tanh_fast(float x) {
  float ax = fabsf(x);
  float e = __expf(ax + ax);
  float t = 1.0f - 2.0f / (e + 1.0f);
  return x < 0.0f ? -t : t;
}

// ---------------- shifted-tap GEMM, cb-outer/tap-inner ---------------------
// C[m,co] = sum_{cb,tap,cl} A[n][p+tap+shift0][cb*cbCI+cl]*Bt[co][(cb*ntaps+tap)*cbCI+cl]
// m=n*P+p (P=1<<logP). A unpadded bf16 [n][P][CI]; out-of-range rows -> zero
// page zp. K-order: ci-block(256) OUTER, tap INNER (tap re-reads L2-resident).
// DEPTH: number of 64-k pairs per barrier (DEPTH*64 k per __syncthreads pair,
// DEPTH*32KB LDS). DEPTH=1 for conv1 (keeps 4-5 blocks/CU); DEPTH=2 for the
// grid-limited tail GEMMs (<=2 blocks/CU anyway -> bigger K-chunk is free and
// halves the vmcnt(0) barrier drains).
// MODE: 0 = plain bias+store, 1 = fused maxpool2 (pairs of rows -> p>>1),
//       2 = fused similarity score (dot rows with uu[c], sigmoid -> outF).
// Grid: blockIdx.x = m-tile (fast; gridDim.x%8==0 -> same-m co-tiles share an
// XCD's L2 copy of A), blockIdx.y = co-tile.
template<int MODE, int DEPTH>
__global__ __launch_bounds__(256) void gemm_tap(
    const bf16* __restrict__ A, const bf16* __restrict__ Bt,
    const float* __restrict__ bias, bf16* __restrict__ Out,
    const bf16* __restrict__ zp,
    int snA, int logP, int logCI, int shift0, int ntaps, int cbCount,
    int cbCI, int pairs, int Ktot, int COt, int snO,
    const float* __restrict__ uu, const float* __restrict__ mlpb,
    float* __restrict__ outF)
{
  __shared__ __align__(16) bf16 Ab[2 * DEPTH][4096];
  __shared__ __align__(16) bf16 Bb[2 * DEPTH][4096];
  const int tid  = threadIdx.x;
  const int wave = tid >> 6, lane = tid & 63;
  const int wr = wave >> 1, wc = wave & 1;
  const int m0  = blockIdx.x << 7;
  const int co0 = blockIdx.y << 7;
  const int P     = 1 << logP;
  const int Pmask = P - 1;
  const int CI    = 1 << logCI;
  f32x4 acc[4][4] = {};

  // staging lane map + XOR k-group swizzle (read side matches; <=2-way = free)
  const int rowL = tid >> 2;
  const int kg   = tid & 3;
  const int fOff = ((kg ^ ((rowL + (rowL >> 2)) & 3)) << 3);

  const int mA0 = m0 + rowL,      nA0 = mA0 >> logP, pA0v = mA0 & Pmask;
  const int mA1 = m0 + rowL + 64, nA1 = mA1 >> logP, pA1v = mA1 & Pmask;
  const bf16* baseA0 = A + nA0 * snA + fOff;
  const bf16* baseA1 = A + nA1 * snA + fOff;
  const bf16* baseB0 = Bt + (co0 + rowL) * Ktot + fOff;
  const bf16* baseB1 = Bt + (co0 + rowL + 64) * Ktot + fOff;
  const bf16* zsrc = zp + fOff;

  const int frow  = lane & 15;
  const int rdOff = (((lane >> 4) ^ ((frow + (frow >> 2)) & 3)) << 3);

  for (int cb = 0; cb < cbCount; ++cb) {
    for (int tap = 0; tap < ntaps; ++tap) {
      const int sh = tap + shift0;
      const int rA0 = pA0v + sh, rA1 = pA1v + sh;
      const bool v0 = (unsigned)rA0 < (unsigned)P;
      const bool v1 = (unsigned)rA1 < (unsigned)P;
      const bf16* pa0 = v0 ? (baseA0 + rA0 * CI + cb * cbCI) : zsrc;
      const bf16* pa1 = v1 ? (baseA1 + rA1 * CI + cb * cbCI) : zsrc;
      const bf16* pb0 = baseB0 + (cb * ntaps + tap) * cbCI;
      const bf16* pb1 = baseB1 + (cb * ntaps + tap) * cbCI;

      for (int kc = 0; kc < pairs; kc += DEPTH) {
#pragma unroll
        for (int h = 0; h < 2 * DEPTH; ++h) {
          gload_lds16(pa0 + 32 * h, &Ab[h][wave * 512]);
          gload_lds16(pa1 + 32 * h, &Ab[h][2048 + wave * 512]);
          gload_lds16(pb0 + 32 * h, &Bb[h][wave * 512]);
          gload_lds16(pb1 + 32 * h, &Bb[h][2048 + wave * 512]);
        }
        if (v0) pa0 += 64 * DEPTH;
        if (v1) pa1 += 64 * DEPTH;
        pb0 += 64 * DEPTH; pb1 += 64 * DEPTH;
        __syncthreads();
#pragma unroll
        for (int h = 0; h < 2 * DEPTH; ++h) {
          bf16x8 af[4], bg[4];
#pragma unroll
          for (int i = 0; i < 4; ++i) {
            af[i] = *(const bf16x8*)&Ab[h][((wr << 6) + (i << 4) + frow) * 32 + rdOff];
            bg[i] = *(const bf16x8*)&Bb[h][((wc << 6) + (i << 4) + frow) * 32 + rdOff];
          }
#pragma unroll
          for (int i = 0; i < 4; ++i)
#pragma unroll
            for (int j = 0; j < 4; ++j)
              acc[i][j] = __builtin_amdgcn_mfma_f32_16x16x32_bf16(af[i], bg[j], acc[i][j], 0, 0, 0);
        }
        __syncthreads();
      }
    }
  }

  // epilogue: C/D layout col=lane&15, row=(lane>>4)*4+reg  [m89-verified]
  const int colL = lane & 15;
  const int rq   = (lane >> 4) << 2;

  if (MODE == 2) {
    // fused similarity score: this block owns full rows (CO == 128, co0 == 0).
    // scratch: per-row partials over the 32 (wc,colL) lane columns.
    float* scr0 = (float*)&Ab[0][0];   // [128][32]
    float* scr1 = (float*)&Bb[0][0];   // [128][32]
    const int n = m0 >> logP;          // one n per block (P == 128)
    const int b = n >> 5;
    const float* u0 = uu + b * 128;
    const float* u1 = uu + 1024 + b * 128;
#pragma unroll
    for (int i = 0; i < 4; ++i) {
#pragma unroll
      for (int r = 0; r < 4; ++r) {
        int rowLcl = (wr << 6) + (i << 4) + rq + r;
        float p0 = 0.0f, p1 = 0.0f;
#pragma unroll
        for (int j = 0; j < 4; ++j) {
          int gco = (wc << 6) + (j << 4) + colL;
          float v = acc[i][j][r];
          p0 += v * u0[gco];
          p1 += v * u1[gco];
        }
        scr0[rowLcl * 32 + (wc << 4) + colL] = p0;
        scr1[rowLcl * 32 + (wc << 4) + colL] = p1;
      }
    }
    __syncthreads();
    {
      int rowLcl = tid >> 1, c = tid & 1;
      const float* s = c ? scr1 : scr0;
      float sum = 0.0f;
#pragma unroll
      for (int k = 0; k < 32; ++k) sum += s[rowLcl * 32 + k];
      float val = 1.0f / (1.0f + __expf(-(sum + mlpb[0])));
      outF[(c ? 32768 : 0) + m0 + rowLcl] = val;
    }
    return;
  }

#pragma unroll
  for (int i = 0; i < 4; ++i) {
    int m = m0 + (wr << 6) + (i << 4) + rq;
    int n = m >> logP, p = m & Pmask;
#pragma unroll
    for (int j = 0; j < 4; ++j) {
      int gco = co0 + (wc << 6) + (j << 4) + colL;
      float bv = bias[gco];
      if (MODE == 1) {
        float v0 = fmaxf(acc[i][j][0], acc[i][j][1]) + bv;
        float v1 = fmaxf(acc[i][j][2], acc[i][j][3]) + bv;
        bf16* o = Out + n * snO + (p >> 1) * COt + gco;
        o[0]   = (bf16)v0;
        o[COt] = (bf16)v1;
      } else {
#pragma unroll
        for (int r = 0; r < 4; ++r)
          Out[n * snO + (p + r) * COt + gco] = (bf16)(acc[i][j][r] + bv);
      }
    }
  }
}

// ---------------- fused prep: weights + biases + cq/uu + batch cvt ----------
// blk < 27468: weight/bias re-layout (idx = blk*256+tid)
// blk in [27468,27492): cq (16 blocks) + uu (8 blocks)
// blk >= 27492: batch fp32->bf16 (16384 blocks)
__global__ __launch_bounds__(256) void prep_all(
    const float* __restrict__ conv1_w, const float* __restrict__ conv2_w,
    const float* __restrict__ sa_wq, const float* __restrict__ sa_wk,
    const float* __restrict__ ca_wk, const float* __restrict__ dc1_w,
    const float* __restrict__ dc2_w, const float* __restrict__ sim1_w,
    const float* __restrict__ c1b, const float* __restrict__ c2b,
    const float* __restrict__ sabq, const float* __restrict__ sabk,
    const float* __restrict__ cabk, const float* __restrict__ d1b,
    const float* __restrict__ d2b,
    const float* __restrict__ c1, const float* __restrict__ c2,
    const float* __restrict__ ca_wq, const float* __restrict__ ca_bq,
    const float* __restrict__ sim2_w, const float* __restrict__ mlp_w,
    const float* __restrict__ batch, bf16* __restrict__ bb16,
    bf16* __restrict__ Bt1, bf16* __restrict__ Bt2, bf16* __restrict__ Bqkc,
    bf16* __restrict__ Btd1, bf16* __restrict__ Btd2, bf16* __restrict__ Bts1,
    float* __restrict__ bias, float* __restrict__ cq, float* __restrict__ uu)
{
  const int blk = blockIdx.x;
  if (blk >= 27492) {
    int idx = ((blk - 27492) * 256 + threadIdx.x) * 8;
    float4 a = *(const float4*)&batch[idx];
    float4 b = *(const float4*)&batch[idx + 4];
    bf16x8 v;
    v[0] = (bf16)a.x; v[1] = (bf16)a.y; v[2] = (bf16)a.z; v[3] = (bf16)a.w;
    v[4] = (bf16)b.x; v[5] = (bf16)b.y; v[6] = (bf16)b.z; v[7] = (bf16)b.w;
    *(bf16x8*)&bb16[idx] = v;
    return;
  }
  if (blk < 27468) {
    int idx = blk * 256 + threadIdx.x;
    if (idx < 3072) {
      // biases f32: [0,512) c1 | [512,768) c2 | [768,1536) qkc |
      // [1536,2560) d1 dup | [2560,2816) d2 dup | [2816,2944) zeros (+zp)
      if (idx < 2944) {
        float v;
        if (idx < 512)       v = c1b[idx];
        else if (idx < 768)  v = c2b[idx - 512];
        else if (idx < 1024) v = sabq[idx - 768];
        else if (idx < 1280) v = sabk[idx - 1024];
        else if (idx < 1536) v = cabk[idx - 1280];
        else if (idx < 2560) v = d1b[(idx - 1536) & 511];
        else if (idx < 2816) v = d2b[(idx - 2560) & 127];
        else                 v = 0.0f;
        bias[idx] = v;
      }
    } else if (idx < 2624512) {
      // Bt1[co][cb4][tap5][cl256] = conv1_w[co][cb*256+cl][tap]
      int i = idx - 3072;
      int co = i / 5120, r = i - co * 5120;
      int cb = r / 1280, r2 = r - cb * 1280;
      int tap = r2 >> 8, cl = r2 & 255;
      Bt1[i] = (bf16)conv1_w[co * 5120 + (cb * 256 + cl) * 5 + tap];
    } else if (idx < 3279872) {
      int i = idx - 2624512;
      int co = i / 2560, r = i - co * 2560;
      int cb = r / 1280, r2 = r - cb * 1280;
      int tap = r2 >> 8, cl = r2 & 255;
      Bt2[i] = (bf16)conv2_w[co * 2560 + (cb * 256 + cl) * 5 + tap];
    } else if (idx < 3476480) {
      int i = idx - 3279872;
      int co = i >> 8, ci = i & 255;
      float v;
      if (co < 256)      v = sa_wq[ci * 256 + co];
      else if (co < 512) v = sa_wk[ci * 256 + (co - 256)];
      else               v = ca_wk[ci * 256 + (co - 512)];
      Bqkc[i] = (bf16)v;
    } else if (idx < 6622208) {
      // Btd1[co][cb4][tap3][cl256]; parity fold:
      // even co: tap1->ki1, tap0->ki3; odd co: tap2->ki0, tap1->ki2
      int i = idx - 3476480;
      int co = i / 3072, r = i - co * 3072;
      int cb = r / 768, r2 = r - cb * 768;
      int tap = r2 >> 8, cl = r2 & 255;
      int ci = cb * 256 + cl;
      int par = co >> 9, c = co & 511;
      int ki = -1;
      if (par == 0) { if (tap == 1) ki = 1; else if (tap == 0) ki = 3; }
      else          { if (tap == 2) ki = 0; else if (tap == 1) ki = 2; }
      Btd1[i] = (ki >= 0) ? (bf16)dc1_w[ci * 2048 + c * 4 + ki] : (bf16)0.0f;
    } else if (idx < 7015424) {
      int i = idx - 6622208;
      int co = i / 1536, r = i - co * 1536;
      int cb = r / 768, r2 = r - cb * 768;
      int tap = r2 >> 8, cl = r2 & 255;
      int ci = cb * 256 + cl;
      int par = co >> 7, c = co & 127;
      int ki = -1;
      if (par == 0) { if (tap == 1) ki = 1; else if (tap == 0) ki = 3; }
      else          { if (tap == 2) ki = 0; else if (tap == 1) ki = 2; }
      Btd2[i] = (ki >= 0) ? (bf16)dc2_w[ci * 512 + c * 4 + ki] : (bf16)0.0f;
    } else {
      int i = idx - 7015424;
      int co = i >> 7, ci = i & 127;
      Bts1[i] = (bf16)sim1_w[ci * 128 + co];
    }
  } else {
    int sub = blk - 27468;
    if (sub < 16) {
      int o = sub * 256 + threadIdx.x;
      int c = o >> 11, b = (o >> 8) & 7, h = o & 255;
      const float* cc = (c ? c2 : c1) + b * 300;
      float acc = ca_bq[h];
      for (int j = 0; j < 300; ++j)
        acc += cc[j] * ca_wq[j * 256 + h];
      cq[o] = acc;
    } else {
      int o = (sub - 16) * 256 + threadIdx.x;
      int c = o >> 10, b = (o >> 7) & 7, m = o & 127;
      const float* cc = (c ? c2 : c1) + b * 300;
      float acc = 0.0f;
      for (int j = 0; j < 300; ++j)
        acc += cc[j] * sim2_w[j * 128 + m];
      uu[o] = acc * mlp_w[m];
    }
  }
}

// ---------------- fused additive attention (one block per n) ----------------
__global__ __launch_bounds__(256) void kattn(
    const bf16* __restrict__ tmp2, const bf16* __restrict__ qkc,
    const float* __restrict__ sa_v, const float* __restrict__ sa_vb,
    const float* __restrict__ ca_v, const float* __restrict__ ca_vb,
    const float* __restrict__ cq, const int* __restrict__ seg,
    bf16* __restrict__ ar)
{
  const int n = blockIdx.x, tid = threadIdx.x;
  __shared__ __align__(16) bf16 t2[32 * 264];
  __shared__ __align__(16) bf16 bufA[32 * 264];
  __shared__ __align__(16) bf16 bufB[32 * 264];
  __shared__ float sv_s[256], cv_s[256];
  __shared__ float sbc[66];
  __shared__ float sbs[32 * 33];
  const int sl = seg[n];

#pragma unroll
  for (int rr = 0; rr < 4; ++rr) {
    int q = tid + (rr << 8);
    int k = q >> 5, c8 = (q & 31) << 3;
    *(uint4*)&t2[k * 264 + c8]   = *(const uint4*)&tmp2[n * 8192 + k * 256 + c8];
    *(uint4*)&bufA[k * 264 + c8] = *(const uint4*)&qkc[n * 24576 + k * 768 + 512 + c8];
  }
  sv_s[tid] = sa_v[tid];
  cv_s[tid] = ca_v[tid];
  __syncthreads();

  if (tid < 64) {
    int c = tid >> 5, k = tid & 31;
    const float* cqr = cq + (c * 8 + (n >> 5)) * 256;
    float acc = 0.0f;
    for (int h = 0; h < 256; ++h)
      acc += tanh_fast(cqr[h] + (float)bufA[k * 264 + h]) * cv_s[h];
    float sc = acc + ca_vb[0];
    sbc[c * 33 + k] = (sl > (k << 2)) ? sc : -1e9f;
  }
  __syncthreads();

#pragma unroll
  for (int rr = 0; rr < 4; ++rr) {
    int q = tid + (rr << 8);
    int k = q >> 5, c8 = (q & 31) << 3;
    *(uint4*)&bufB[k * 264 + c8] = *(const uint4*)&qkc[n * 24576 + k * 768 + c8];
    *(uint4*)&bufA[k * 264 + c8] = *(const uint4*)&qkc[n * 24576 + k * 768 + 256 + c8];
  }
  if (tid < 2) {
    float* row = &sbc[tid * 33];
    float mx = -1e30f;
    for (int k = 0; k < 32; ++k) mx = fmaxf(mx, row[k]);
    float sum = 0.0f;
    for (int k = 0; k < 32; ++k) { float e = __expf(row[k] - mx); row[k] = e; sum += e; }
    float inv = 1.0f / sum;
    for (int k = 0; k < 32; ++k) row[k] *= inv;
  }
  __syncthreads();

  {
    int col = tid;
    float rr0 = 0.0f, rr1 = 0.0f;
    for (int k = 0; k < 32; ++k) {
      float tv = (float)t2[k * 264 + col];
      rr0 += sbc[k] * tv;
      rr1 += sbc[33 + k] * tv;
    }
    bf16 b0 = (bf16)rr0, b1 = (bf16)rr1;
    bf16* arn = ar + n * 32768;
    for (int q = 0; q < 32; ++q) {
      arn[q * 1024 + col]       = t2[q * 264 + col];
      arn[q * 1024 + 512 + col] = b0;
      arn[q * 1024 + 768 + col] = b1;
    }
  }
  {
    float svb = sa_vb[0];
#pragma unroll
    for (int rr = 0; rr < 4; ++rr) {
      int id = tid + (rr << 8);
      int q = id >> 5, k = id & 31;
      float acc = 0.0f;
      for (int h = 0; h < 256; ++h)
        acc += tanh_fast((float)bufB[q * 264 + h] + (float)bufA[k * 264 + h]) * sv_s[h];
      float sc = acc + svb;
      sbs[q * 33 + k] = (sl > (k << 2)) ? sc : -1e9f;
    }
  }
  __syncthreads();

  if (tid < 32) {
    float* row = &sbs[tid * 33];
    float mx = -1e30f;
    for (int k = 0; k < 32; ++k) mx = fmaxf(mx, row[k]);
    float sum = 0.0f;
    for (int k = 0; k < 32; ++k) { float e = __expf(row[k] - mx); row[k] = e; sum += e; }
    float inv = 1.0f / sum;
    for (int k = 0; k < 32; ++k) row[k] *= inv;
  }
  __syncthreads();

  {
    int col = tid;
    bf16* arn = ar + n * 32768;
    for (int q = 0; q < 32; ++q) {
      float acc = 0.0f;
      for (int k = 0; k < 32; ++k)
        acc += sbs[q * 33 + k] * (float)t2[k * 264 + col];
      arn[q * 1024 + 256 + col] = (bf16)acc;
    }
  }
}

// ---------------- launch ----------------
extern "C" void kernel_launch(void* const* d_in, const int* in_sizes, int n_in,
                              void* d_out, int out_size, void* d_ws, size_t ws_size,
                              hipStream_t stream) {
  const float* batch    = (const float*)d_in[0];
  const float* concept1 = (const float*)d_in[1];
  const float* concept2 = (const float*)d_in[2];
  const int*   seg      = (const int*)d_in[3];
  const float* conv1_w  = (const float*)d_in[4];
  const float* conv1_b  = (const float*)d_in[5];
  const float* conv2_w  = (const float*)d_in[6];
  const float* conv2_b  = (const float*)d_in[7];
  const float* sa_wq    = (const float*)d_in[8];
  const float* sa_bq    = (const float*)d_in[9];
  const float* sa_wk    = (const float*)d_in[10];
  const float* sa_bk    = (const float*)d_in[11];
  const float* sa_v     = (const float*)d_in[12];
  const float* sa_vb    = (const float*)d_in[13];
  const float* ca_wq    = (const float*)d_in[14];
  const float* ca_bq    = (const float*)d_in[15];
  const float* ca_wk    = (const float*)d_in[16];
  const float* ca_bk    = (const float*)d_in[17];
  const float* ca_v     = (const float*)d_in[18];
  const float* ca_vb    = (const float*)d_in[19];
  const float* dc1_w    = (const float*)d_in[20];
  const float* dc1_b    = (const float*)d_in[21];
  const float* dc2_w    = (const float*)d_in[22];
  const float* dc2_b    = (const float*)d_in[23];
  const float* sim1_w   = (const float*)d_in[24];
  const float* sim2_w   = (const float*)d_in[25];
  const float* mlp_w    = (const float*)d_in[26];
  const float* mlp_b    = (const float*)d_in[27];

  char* ws = (char*)d_ws;
  bf16* bb16  = (bf16*)(ws + 0);
  bf16* qkcb  = (bf16*)(ws + 0);
  bf16* arb   = (bf16*)(ws + 12582912);
  bf16* d1    = (bf16*)(ws + 29360128);
  bf16* rbuf  = (bf16*)(ws + 46137344);
  bf16* t1    = (bf16*)(ws + 67108864);
  bf16* tmp2b = (bf16*)(ws + 83886080);
  bf16* Bt1   = (bf16*)(ws + 88080384);
  bf16* Bt2   = (bf16*)(ws + 93323264);
  bf16* Bqkc  = (bf16*)(ws + 94633984);
  bf16* Btd1  = (bf16*)(ws + 95027200);
  bf16* Btd2  = (bf16*)(ws + 101318656);
  bf16* Bts1  = (bf16*)(ws + 102105088);
  float* biasall = (float*)(ws + 102137856);
  float* cqb  = (float*)(ws + 102149632);
  float* uub  = (float*)(ws + 102166016);
  const bf16* zp = (const bf16*)(biasall + 2816);  // 128 f32 zeros = 256 bf16 zeros
  float* outp = (float*)d_out;

  // fused prep: weights re-layout + biases + cq/uu + batch fp32->bf16
  prep_all<<<43876, 256, 0, stream>>>(
      conv1_w, conv2_w, sa_wq, sa_wk, ca_wk, dc1_w, dc2_w, sim1_w,
      conv1_b, conv2_b, sa_bq, sa_bk, ca_bk, dc1_b, dc2_b,
      concept1, concept2, ca_wq, ca_bq, sim2_w, mlp_w,
      batch, bb16,
      Bt1, Bt2, Bqkc, Btd1, Btd2, Bts1, biasall, cqb, uub);

  // conv1 + pool: cb4 x tap5, DEPTH=1 (4 blocks/CU) -> t1 [256][64][512]
  gemm_tap<1, 1><<<dim3(256, 4), 256, 0, stream>>>(
      bb16, Bt1, biasall + 0, t1, zp, 131072, 7, 10, -2, 5, 4, 256, 4, 5120, 512, 32768,
      nullptr, nullptr, nullptr);

  // conv2 + pool: DEPTH=2 (grid-limited) -> tmp2 [256][32][256]
  gemm_tap<1, 2><<<dim3(128, 2), 256, 0, stream>>>(
      t1, Bt2, biasall + 512, tmp2b, zp, 32768, 6, 9, -2, 5, 2, 256, 4, 2560, 256, 8192,
      nullptr, nullptr, nullptr);

  // fused q/k/ck projection: DEPTH=2 -> qkc [256][32][768]
  gemm_tap<0, 2><<<dim3(64, 6), 256, 0, stream>>>(
      tmp2b, Bqkc, biasall + 768, qkcb, zp, 8192, 5, 8, 0, 1, 1, 256, 4, 256, 768, 24576,
      nullptr, nullptr, nullptr);

  // attention -> ar [256][32][1024]
  kattn<<<256, 256, 0, stream>>>(tmp2b, qkcb, sa_v, sa_vb, ca_v, ca_vb, cqb, seg, arb);

  // deconv1: DEPTH=2 -> d1 [256][64][1024] (parity-interleaved)
  gemm_tap<0, 2><<<dim3(64, 8), 256, 0, stream>>>(
      arb, Btd1, biasall + 1536, d1, zp, 32768, 5, 10, -1, 3, 4, 256, 4, 3072, 1024, 32768,
      nullptr, nullptr, nullptr);

  // deconv2: DEPTH=2 -> rbuf [256][64][256] (parity-interleaved)
  gemm_tap<0, 2><<<dim3(128, 2), 256, 0, stream>>>(
      d1, Btd2, biasall + 2560, rbuf, zp, 32768, 6, 9, -1, 3, 2, 256, 4, 1536, 256, 16384,
      nullptr, nullptr, nullptr);

  // sim1 + fused score: DEPTH=2, MODE=2 -> out (fp32, both concepts)
  gemm_tap<2, 2><<<dim3(256, 1), 256, 0, stream>>>(
      rbuf, Bts1, biasall + 2816, nullptr, zp, 16384, 7, 7, 0, 1, 1, 128, 2, 128, 128, 16384,
      uub, mlp_b, outp);
}